// Round 4
// baseline (238.382 us; speedup 1.0000x reference)
//
#include <hip/hip_runtime.h>
#include <math.h>

typedef __bf16 bf16x8 __attribute__((ext_vector_type(8)));
typedef __bf16 bf16x2 __attribute__((ext_vector_type(2)));
typedef float f32x4 __attribute__((ext_vector_type(4)));

namespace {
constexpr int kB = 128, kS = 256, kD = 128, kH = 4;
constexpr float kEps = 1e-6f;
constexpr float kScale = 0.17677669529663687f;  // 1/sqrt(32)
constexpr float kNeg = -1000000000.0f;
constexpr size_t kSZ = (size_t)kB * kS * kD;    // 4,194,304
}

// ---------------------------------------------------------------------------
// Weight transpose + convert: Wt[l*4+mtx][n][k] = (bf16) W[l][k][n]
// ---------------------------------------------------------------------------
__global__ __launch_bounds__(256) void wtrans(
    const float* __restrict__ Wq, const float* __restrict__ Wk,
    const float* __restrict__ Wv, const float* __restrict__ Wo,
    __bf16* __restrict__ Wt)
{
    const int mtx = blockIdx.x & 3, l = blockIdx.x >> 2;
    const float* W = (mtx == 0 ? Wq : mtx == 1 ? Wk : mtx == 2 ? Wv : Wo) +
                     (size_t)l * kD * kD;
    __bf16* o = Wt + (size_t)blockIdx.x * kD * kD;
    for (int idx = threadIdx.x; idx < kD * kD; idx += 256) {
        const int k = idx >> 7, n = idx & 127;
        o[n * 128 + k] = (__bf16)W[idx];
    }
}

// ---------------------------------------------------------------------------
// No-LDS fused QKV GEMM. Block = 4 waves x 16 rows = 64 rows; grid 512.
// A-fragments (4, reused for all 3 matrices) and W B-fragments are loaded
// per-lane directly from global (W is 96KB, L1/L2-hot across all blocks).
// No LDS, no __syncthreads, no staging writes.
// ---------------------------------------------------------------------------
template <bool F32A>
__global__ __launch_bounds__(256) void qkv_gemm(
    const void* __restrict__ Av, const __bf16* __restrict__ Wt,
    const float* __restrict__ bq, const float* __restrict__ bk,
    const float* __restrict__ bv, __bf16* __restrict__ Qb,
    __bf16* __restrict__ Kb, __bf16* __restrict__ Vb)
{
    const int t = threadIdx.x;
    const int w = t >> 6, l = t & 63, lo = l & 15, g = l >> 4;
    const size_t m0 = (size_t)blockIdx.x * 64 + w * 16;

    bf16x8 af[4];
#pragma unroll
    for (int ks = 0; ks < 4; ++ks) {
        if constexpr (F32A) {
            const float* src = (const float*)Av + (m0 + lo) * 128 + (g + 4 * ks) * 8;
            const float4 a0 = *(const float4*)src;
            const float4 a1 = *(const float4*)(src + 4);
            bf16x8 o;
            o[0] = (__bf16)a0.x; o[1] = (__bf16)a0.y; o[2] = (__bf16)a0.z; o[3] = (__bf16)a0.w;
            o[4] = (__bf16)a1.x; o[5] = (__bf16)a1.y; o[6] = (__bf16)a1.z; o[7] = (__bf16)a1.w;
            af[ks] = o;
        } else {
            af[ks] = *(const bf16x8*)((const __bf16*)Av + (m0 + lo) * 128 + (g + 4 * ks) * 8);
        }
    }

    const float* biases[3] = {bq, bk, bv};
    __bf16* outs[3] = {Qb, Kb, Vb};

#pragma unroll
    for (int m = 0; m < 3; ++m) {
        const __bf16* Wm = Wt + m * 16384;
        f32x4 acc[8];
#pragma unroll
        for (int ni = 0; ni < 8; ++ni) acc[ni] = f32x4{0.f, 0.f, 0.f, 0.f};
#pragma unroll
        for (int ks = 0; ks < 4; ++ks)
#pragma unroll
            for (int ni = 0; ni < 8; ++ni) {
                const bf16x8 bv8 =
                    *(const bf16x8*)(Wm + (ni * 16 + lo) * 128 + (g + 4 * ks) * 8);
                acc[ni] = __builtin_amdgcn_mfma_f32_16x16x32_bf16(af[ks], bv8, acc[ni], 0, 0, 0);
            }
#pragma unroll
        for (int ni = 0; ni < 8; ++ni) {
            const float bc = biases[m][ni * 16 + lo];
#pragma unroll
            for (int r = 0; r < 4; ++r)
                outs[m][(m0 + g * 4 + r) * 128 + ni * 16 + lo] = (__bf16)(acc[ni][r] + bc);
        }
    }
}

// ---------------------------------------------------------------------------
// MFMA attention. Grid 2048 = (b, h, strip); wave owns 16 queries.
// S^T = K @ Q^T, full softmax in regs, P->LDS (XOR-swizzled, conflict-free
// b128 reads), O = P @ V (V^T tile). WEIGHTS: lanes holding q=255 emit the
// normalized softmax row; total_l1 = L*B*H = 1024 exactly.
// ---------------------------------------------------------------------------
template <int WEIGHTS>
__global__ __launch_bounds__(256) void attn_mfma(
    const __bf16* __restrict__ Qb, const __bf16* __restrict__ Kb,
    const __bf16* __restrict__ Vb, const float* __restrict__ mask,
    __bf16* __restrict__ ctx, float* __restrict__ wout,
    float* __restrict__ l1out)
{
    __shared__ __bf16 Pl[4][16 * 256];  // per-wave 16q x 256k, 16B-chunk XOR swz
    __shared__ __bf16 Vt[32][264];
    __shared__ float mb[256];

    const int t = threadIdx.x;
    const int w = t >> 6, l = t & 63, lo = l & 15, g = l >> 4;
    const int b = blockIdx.x >> 4;
    const int h = (blockIdx.x >> 2) & 3;
    const int strip = blockIdx.x & 3;
    const size_t base = ((size_t)b * 256) * 128 + h * 32;

    mb[t] = mask[b * 256 + t] * kNeg;

#pragma unroll
    for (int p = 0; p < 4; ++p) {
        const int key = p * 64 + (t >> 2);
        const int d0 = (t & 3) * 8;
        const bf16x8 v = *(const bf16x8*)(Vb + base + (size_t)key * 128 + d0);
#pragma unroll
        for (int i = 0; i < 8; ++i) Vt[d0 + i][key] = v[i];
    }

    const int q0 = strip * 64 + w * 16;
    const bf16x8 qf = *(const bf16x8*)(Qb + base + (size_t)(q0 + lo) * 128 + g * 8);
    __syncthreads();

    f32x4 s[16];
#pragma unroll
    for (int f = 0; f < 16; ++f) {
        const bf16x8 kf =
            *(const bf16x8*)(Kb + base + (size_t)(f * 16 + lo) * 128 + g * 8);
        s[f] = __builtin_amdgcn_mfma_f32_16x16x32_bf16(
            kf, qf, f32x4{0.f, 0.f, 0.f, 0.f}, 0, 0, 0);
    }

    float mx = -1e30f;
#pragma unroll
    for (int f = 0; f < 16; ++f) {
        const f32x4 mk = *(const f32x4*)&mb[f * 16 + g * 4];
#pragma unroll
        for (int r = 0; r < 4; ++r) {
            s[f][r] = s[f][r] * kScale + mk[r];
            mx = fmaxf(mx, s[f][r]);
        }
    }
    mx = fmaxf(mx, __shfl_xor(mx, 16, 64));
    mx = fmaxf(mx, __shfl_xor(mx, 32, 64));

    float ls = 0.f;
#pragma unroll
    for (int f = 0; f < 16; ++f)
#pragma unroll
        for (int r = 0; r < 4; ++r) {
            const float p = __expf(s[f][r] - mx);
            s[f][r] = p;
            ls += p;
        }
    ls += __shfl_xor(ls, 16, 64);
    ls += __shfl_xor(ls, 32, 64);

    if constexpr (WEIGHTS) {
        if (strip == 3 && w == 3 && lo == 15) {
            const float inv = 1.f / ls;
            float* wrow = wout + ((size_t)b * 4 + h) * 256;
#pragma unroll
            for (int f = 0; f < 16; ++f)
#pragma unroll
                for (int r = 0; r < 4; ++r)
                    wrow[f * 16 + g * 4 + r] = s[f][r] * inv;
        }
        if (blockIdx.x == 0 && t == 0) l1out[0] = 1024.0f;
    }

    // P -> LDS, XOR-swizzled 16B chunks: elem e = f*16+4g+2pr, chunk = e>>3
#pragma unroll
    for (int f = 0; f < 16; ++f)
#pragma unroll
        for (int pr = 0; pr < 2; ++pr) {
            bf16x2 pk;
            pk[0] = (__bf16)s[f][2 * pr];
            pk[1] = (__bf16)s[f][2 * pr + 1];
            const int e = f * 16 + 4 * g + 2 * pr;
            const int addr = lo * 256 + (((e >> 3) ^ (lo & 7)) << 3) + (e & 7);
            *(bf16x2*)&Pl[w][addr] = pk;
        }
    __syncthreads();

    f32x4 o[2] = {f32x4{0.f, 0.f, 0.f, 0.f}, f32x4{0.f, 0.f, 0.f, 0.f}};
#pragma unroll
    for (int ks = 0; ks < 8; ++ks) {
        const int cc = ks * 4 + g;
        const bf16x8 pa = *(const bf16x8*)&Pl[w][lo * 256 + ((cc ^ (lo & 7)) << 3)];
#pragma unroll
        for (int nf = 0; nf < 2; ++nf) {
            const bf16x8 bv = *(const bf16x8*)&Vt[nf * 16 + lo][ks * 32 + g * 8];
            o[nf] = __builtin_amdgcn_mfma_f32_16x16x32_bf16(pa, bv, o[nf], 0, 0, 0);
        }
    }

#pragma unroll
    for (int r = 0; r < 4; ++r) {
        const float inv = 1.f / __shfl(ls, 4 * g + r, 64);
        const size_t q = q0 + g * 4 + r;
#pragma unroll
        for (int nf = 0; nf < 2; ++nf)
            ctx[base + q * 128 + nf * 16 + lo] = (__bf16)(o[nf][r] * inv);
    }
}

// ---------------------------------------------------------------------------
// No-LDS O-projection + residual + LayerNorm1 -> O1 (bf16).
// Same wave layout as qkv_gemm; Wo B-fragments from global (L1/L2-hot).
// ---------------------------------------------------------------------------
__global__ __launch_bounds__(256) void oproj_ln(
    const __bf16* __restrict__ A, const __bf16* __restrict__ Wt,
    const float* __restrict__ bias, const float* __restrict__ resid,
    const float* __restrict__ gamma, const float* __restrict__ beta,
    __bf16* __restrict__ out)
{
    const int t = threadIdx.x;
    const int w = t >> 6, l = t & 63, lo = l & 15, g = l >> 4;
    const size_t m0 = (size_t)blockIdx.x * 64 + w * 16;

    bf16x8 af[4];
#pragma unroll
    for (int ks = 0; ks < 4; ++ks)
        af[ks] = *(const bf16x8*)(A + (m0 + lo) * 128 + (g + 4 * ks) * 8);

    f32x4 acc[8];
#pragma unroll
    for (int ni = 0; ni < 8; ++ni) acc[ni] = f32x4{0.f, 0.f, 0.f, 0.f};
#pragma unroll
    for (int ks = 0; ks < 4; ++ks)
#pragma unroll
        for (int ni = 0; ni < 8; ++ni) {
            const bf16x8 bv8 =
                *(const bf16x8*)(Wt + (ni * 16 + lo) * 128 + (g + 4 * ks) * 8);
            acc[ni] = __builtin_amdgcn_mfma_f32_16x16x32_bf16(af[ks], bv8, acc[ni], 0, 0, 0);
        }

    float bcol[8], ga[8], be[8];
#pragma unroll
    for (int ni = 0; ni < 8; ++ni) {
        bcol[ni] = bias[ni * 16 + lo];
        ga[ni] = gamma[ni * 16 + lo];
        be[ni] = beta[ni * 16 + lo];
    }

    float vv[4][8];
    float s[4] = {0, 0, 0, 0}, s2[4] = {0, 0, 0, 0};
#pragma unroll
    for (int r = 0; r < 4; ++r) {
        const size_t mm = m0 + g * 4 + r;
#pragma unroll
        for (int ni = 0; ni < 8; ++ni) {
            const float x = acc[ni][r] + bcol[ni] + resid[mm * 128 + ni * 16 + lo];
            vv[r][ni] = x; s[r] += x; s2[r] += x * x;
        }
    }
#pragma unroll
    for (int r = 0; r < 4; ++r)
#pragma unroll
        for (int o = 1; o < 16; o <<= 1) {
            s[r] += __shfl_xor(s[r], o, 64);
            s2[r] += __shfl_xor(s2[r], o, 64);
        }
#pragma unroll
    for (int r = 0; r < 4; ++r) {
        const float mu = s[r] * (1.f / 128.f);
        const float var = s2[r] * (1.f / 128.f) - mu * mu;
        const float rs = rsqrtf(var + kEps);
        const size_t mm = m0 + g * 4 + r;
#pragma unroll
        for (int ni = 0; ni < 8; ++ni)
            out[mm * 128 + ni * 16 + lo] =
                (__bf16)(ga[ni] * (vv[r][ni] - mu) * rs + be[ni]);
    }
}

// ---------------------------------------------------------------------------
// Fused tree aggregation + residual + LayerNorm2. One block per batch b.
// e[255][128] f32 in LDS (130.5 KB); o1 re-read from global (L2-hot) for the
// residual. Writes x (f32, d_out) and optionally bf16 copy for next layer.
// ---------------------------------------------------------------------------
__global__ __launch_bounds__(512) void tree_ln(
    const __bf16* __restrict__ o1, const float* __restrict__ gamma,
    const float* __restrict__ beta, float* __restrict__ xo,
    __bf16* __restrict__ xb, int write_xb)
{
    __shared__ float e[255 * 128];
    const int b = blockIdx.x;
    const int t = threadIdx.x;
    const __bf16* ob = o1 + (size_t)b * 256 * 128;

    // load 255 rows (4080 bf16x8 chunks) -> f32 LDS
    for (int ci = t; ci < 4080; ci += 512) {
        const bf16x8 v = *(const bf16x8*)(ob + ci * 8);
#pragma unroll
        for (int i = 0; i < 8; ++i) e[ci * 8 + i] = (float)v[i];
    }
    __syncthreads();

    // bottom-up tree: e[p] = tanh(e[2p+1] + e[2p+2])
    for (int lvl = 6; lvl >= 0; --lvl) {
        const int p0 = (1 << lvl) - 1;
        const int total = (1 << lvl) * 128;
        for (int wk = t; wk < total; wk += 512) {
            const int p = p0 + (wk >> 7), f = wk & 127;
            e[p * 128 + f] = tanhf(e[(2 * p + 1) * 128 + f] + e[(2 * p + 2) * 128 + f]);
        }
        __syncthreads();
    }

    // y = o1 + tab; LayerNorm per row (wave per row, 2 cols/lane)
    const int wv = t >> 6, lane = t & 63;
    const float2 gv = *(const float2*)(gamma + lane * 2);
    const float2 bb = *(const float2*)(beta + lane * 2);
    for (int row = wv; row < 256; row += 8) {
        const bf16x2 v = *(const bf16x2*)(ob + (size_t)row * 128 + lane * 2);
        const float o0 = (float)v[0], o1v = (float)v[1];
        float y0, y1;
        if (row < 255) {
            y0 = o0 + e[row * 128 + lane * 2];
            y1 = o1v + e[row * 128 + lane * 2 + 1];
        } else {
            y0 = o0 + o0;
            y1 = o1v + o1v;
        }
        float s = y0 + y1, s2 = y0 * y0 + y1 * y1;
#pragma unroll
        for (int o = 1; o < 64; o <<= 1) {
            s += __shfl_xor(s, o, 64);
            s2 += __shfl_xor(s2, o, 64);
        }
        const float mu = s * (1.f / 128.f);
        const float var = s2 * (1.f / 128.f) - mu * mu;
        const float rs = rsqrtf(var + kEps);
        const float r0 = gv.x * (y0 - mu) * rs + bb.x;
        const float r1 = gv.y * (y1 - mu) * rs + bb.y;
        float2 o2; o2.x = r0; o2.y = r1;
        *(float2*)(xo + ((size_t)b * 256 + row) * 128 + lane * 2) = o2;
        if (write_xb) {
            bf16x2 xo2; xo2[0] = (__bf16)r0; xo2[1] = (__bf16)r1;
            *(bf16x2*)(xb + ((size_t)b * 256 + row) * 128 + lane * 2) = xo2;
        }
    }
}

// ---------------------------------------------------------------------------
extern "C" void kernel_launch(void* const* d_in, const int* in_sizes, int n_in,
                              void* d_out, int out_size, void* d_ws, size_t ws_size,
                              hipStream_t stream)
{
    (void)in_sizes; (void)n_in; (void)out_size; (void)ws_size;

    const float* x_in = (const float*)d_in[0];
    const float* mask = (const float*)d_in[1];
    const float* Wq = (const float*)d_in[5];
    const float* bq = (const float*)d_in[6];
    const float* Wk = (const float*)d_in[7];
    const float* bk = (const float*)d_in[8];
    const float* Wv = (const float*)d_in[9];
    const float* bv = (const float*)d_in[10];
    const float* Wo = (const float*)d_in[11];
    const float* bo = (const float*)d_in[12];
    const float* g1 = (const float*)d_in[13];
    const float* b1 = (const float*)d_in[14];
    const float* g2 = (const float*)d_in[15];
    const float* b2 = (const float*)d_in[16];

    float* out_x = (float*)d_out;
    float* out_l1 = out_x + kSZ;
    float* out_w = out_l1 + 1;

    char* wsb = (char*)d_ws;
    __bf16* Qb = (__bf16*)wsb;
    __bf16* Kb = (__bf16*)(wsb + 1 * kSZ * 2);
    __bf16* Vb = (__bf16*)(wsb + 2 * kSZ * 2);
    __bf16* CX = (__bf16*)(wsb + 3 * kSZ * 2);
    __bf16* O1 = (__bf16*)(wsb + 4 * kSZ * 2);
    __bf16* xb = (__bf16*)(wsb + 5 * kSZ * 2);
    __bf16* Wt = (__bf16*)(wsb + 6 * kSZ * 2);   // 8 * 16384 bf16

    wtrans<<<8, 256, 0, stream>>>(Wq, Wk, Wv, Wo, Wt);

    for (int l = 0; l < 2; ++l) {
        const float* xi = (l == 0) ? x_in : out_x;  // f32 residual source
        const __bf16* WtL = Wt + (size_t)l * 4 * kD * kD;
        const size_t bof = (size_t)l * kD;

        if (l == 0)
            qkv_gemm<true><<<512, 256, 0, stream>>>(x_in, WtL, bq + bof, bk + bof,
                                                    bv + bof, Qb, Kb, Vb);
        else
            qkv_gemm<false><<<512, 256, 0, stream>>>(xb, WtL, bq + bof, bk + bof,
                                                     bv + bof, Qb, Kb, Vb);

        if (l == 0)
            attn_mfma<0><<<2048, 256, 0, stream>>>(Qb, Kb, Vb, mask, CX,
                                                   nullptr, nullptr);
        else
            attn_mfma<1><<<2048, 256, 0, stream>>>(Qb, Kb, Vb, mask, CX,
                                                   out_w, out_l1);

        oproj_ln<<<512, 256, 0, stream>>>(CX, WtL + 3 * kD * kD, bo + bof, xi,
                                          g1 + bof, b1 + bof, O1);

        tree_ln<<<128, 512, 0, stream>>>(O1, g2 + bof, b2 + bof, out_x, xb,
                                         l == 0 ? 1 : 0);
    }
}

// Round 5
// 169.585 us; speedup vs baseline: 1.4057x; 1.4057x over previous
//
#include <hip/hip_runtime.h>
#include <math.h>

typedef __bf16 bf16x8 __attribute__((ext_vector_type(8)));
typedef __bf16 bf16x2 __attribute__((ext_vector_type(2)));
typedef float f32x4 __attribute__((ext_vector_type(4)));

namespace {
constexpr int kB = 128, kS = 256, kD = 128, kH = 4;
constexpr float kEps = 1e-6f;
constexpr float kScale = 0.17677669529663687f;  // 1/sqrt(32)
constexpr float kNeg = -1000000000.0f;
constexpr size_t kSZ = (size_t)kB * kS * kD;    // 4,194,304
}

// ---------------------------------------------------------------------------
// Weight transpose + convert: Wt[l*4+mtx][n][k] = (bf16) W[l][k][n]
// ---------------------------------------------------------------------------
__global__ __launch_bounds__(256) void wtrans(
    const float* __restrict__ Wq, const float* __restrict__ Wk,
    const float* __restrict__ Wv, const float* __restrict__ Wo,
    __bf16* __restrict__ Wt)
{
    const int mtx = blockIdx.x & 3, l = blockIdx.x >> 2;
    const float* W = (mtx == 0 ? Wq : mtx == 1 ? Wk : mtx == 2 ? Wv : Wo) +
                     (size_t)l * kD * kD;
    __bf16* o = Wt + (size_t)blockIdx.x * kD * kD;
    for (int idx = threadIdx.x; idx < kD * kD; idx += 256) {
        const int k = idx >> 7, n = idx & 127;
        o[n * 128 + k] = (__bf16)W[idx];
    }
}

// ---------------------------------------------------------------------------
// Fused QKV GEMM, 64KB LDS (2 blocks/CU): A tile (32KB) + ONE W tile buffer
// (32KB) re-staged for each of Q,K,V. A-fragments loaded once, reused x3.
// 512 threads / 8 waves; wave owns 16 rows x 128 cols.
// 16B-chunk XOR swizzle (chunk ^= row&7) -> conflict-free ds_read_b128 (T2).
// ---------------------------------------------------------------------------
__global__ __launch_bounds__(512, 4) void qkv_gemm(
    const float* __restrict__ A, const __bf16* __restrict__ Wt,
    const float* __restrict__ bq, const float* __restrict__ bk,
    const float* __restrict__ bv, __bf16* __restrict__ Qb,
    __bf16* __restrict__ Kb, __bf16* __restrict__ Vb)
{
    __shared__ __bf16 As[128 * 128];
    __shared__ __bf16 Ws[128 * 128];

    const int t = threadIdx.x;
    const int w = t >> 6, l = t & 63, lo = l & 15, g = l >> 4;
    const size_t m0 = (size_t)blockIdx.x * 128;

    // stage A: f32 global (2x float4) -> bf16x8 swizzled LDS chunk
#pragma unroll
    for (int p = 0; p < 4; ++p) {
        const int ci = p * 512 + t;
        const int row = ci >> 4, c = ci & 15;
        const float* src = A + (m0 + row) * 128 + c * 8;
        const float4 a0 = *(const float4*)src;
        const float4 a1 = *(const float4*)(src + 4);
        bf16x8 o;
        o[0] = (__bf16)a0.x; o[1] = (__bf16)a0.y; o[2] = (__bf16)a0.z; o[3] = (__bf16)a0.w;
        o[4] = (__bf16)a1.x; o[5] = (__bf16)a1.y; o[6] = (__bf16)a1.z; o[7] = (__bf16)a1.w;
        *(bf16x8*)&As[row * 128 + (c ^ (row & 7)) * 8] = o;
    }
    // stage W0
#pragma unroll
    for (int p = 0; p < 4; ++p) {
        const int ci = p * 512 + t;
        const int row = ci >> 4, c = ci & 15;
        *(bf16x8*)&Ws[row * 128 + (c ^ (row & 7)) * 8] =
            *(const bf16x8*)(Wt + row * 128 + c * 8);
    }
    __syncthreads();

    // A-fragments once, reused across the 3 matrices
    bf16x8 av[4];
    {
        const int arow = w * 16 + lo;
#pragma unroll
        for (int ks = 0; ks < 4; ++ks)
            av[ks] = *(const bf16x8*)&As[arow * 128 + ((g + 4 * ks) ^ (arow & 7)) * 8];
    }

    const float* biases[3] = {bq, bk, bv};
    __bf16* outs[3] = {Qb, Kb, Vb};

#pragma unroll
    for (int m = 0; m < 3; ++m) {
        f32x4 acc[8];
#pragma unroll
        for (int ni = 0; ni < 8; ++ni) acc[ni] = f32x4{0.f, 0.f, 0.f, 0.f};
#pragma unroll
        for (int ks = 0; ks < 4; ++ks)
#pragma unroll
            for (int ni = 0; ni < 8; ++ni) {
                const int brow = ni * 16 + lo;
                const bf16x8 bv8 =
                    *(const bf16x8*)&Ws[brow * 128 + ((g + 4 * ks) ^ (brow & 7)) * 8];
                acc[ni] = __builtin_amdgcn_mfma_f32_16x16x32_bf16(av[ks], bv8, acc[ni], 0, 0, 0);
            }
#pragma unroll
        for (int ni = 0; ni < 8; ++ni) {
            const float bc = biases[m][ni * 16 + lo];
#pragma unroll
            for (int r = 0; r < 4; ++r)
                outs[m][(m0 + w * 16 + g * 4 + r) * 128 + ni * 16 + lo] =
                    (__bf16)(acc[ni][r] + bc);
        }
        if (m < 2) {
            __syncthreads();  // all waves done reading Ws
#pragma unroll
            for (int p = 0; p < 4; ++p) {
                const int ci = p * 512 + t;
                const int row = ci >> 4, c = ci & 15;
                *(bf16x8*)&Ws[row * 128 + (c ^ (row & 7)) * 8] =
                    *(const bf16x8*)(Wt + (m + 1) * 16384 + row * 128 + c * 8);
            }
            __syncthreads();
        }
    }
}

// ---------------------------------------------------------------------------
// MFMA attention. Grid 2048 = (b, h, strip); wave owns 16 queries.
// S^T = K @ Q^T, full softmax in regs, P->LDS (XOR-swizzled, conflict-free
// b128 reads), O = P @ V (V^T tile, stride 268 = 2-way-max banks).
// WEIGHTS: lanes holding q=255 emit the normalized softmax row;
// total_l1 = L*B*H = 1024 exactly (softmax rows positive, sum to 1).
// ---------------------------------------------------------------------------
template <int WEIGHTS>
__global__ __launch_bounds__(256) void attn_mfma(
    const __bf16* __restrict__ Qb, const __bf16* __restrict__ Kb,
    const __bf16* __restrict__ Vb, const float* __restrict__ mask,
    __bf16* __restrict__ ctx, float* __restrict__ wout,
    float* __restrict__ l1out)
{
    __shared__ __bf16 Pl[4][16 * 256];  // per-wave 16q x 256k, 16B-chunk XOR swz
    __shared__ __bf16 Vt[32][268];      // V^T, stride 268: 2-way max on rd+wr
    __shared__ float mb[256];

    const int t = threadIdx.x;
    const int w = t >> 6, l = t & 63, lo = l & 15, g = l >> 4;
    const int b = blockIdx.x >> 4;
    const int h = (blockIdx.x >> 2) & 3;
    const int strip = blockIdx.x & 3;
    const size_t base = ((size_t)b * 256) * 128 + h * 32;

    mb[t] = mask[b * 256 + t] * kNeg;

#pragma unroll
    for (int p = 0; p < 4; ++p) {
        const int key = p * 64 + (t >> 2);
        const int d0 = (t & 3) * 8;
        const bf16x8 v = *(const bf16x8*)(Vb + base + (size_t)key * 128 + d0);
#pragma unroll
        for (int i = 0; i < 8; ++i) Vt[d0 + i][key] = v[i];
    }

    const int q0 = strip * 64 + w * 16;
    const bf16x8 qf = *(const bf16x8*)(Qb + base + (size_t)(q0 + lo) * 128 + g * 8);
    __syncthreads();

    f32x4 s[16];
#pragma unroll
    for (int f = 0; f < 16; ++f) {
        const bf16x8 kf =
            *(const bf16x8*)(Kb + base + (size_t)(f * 16 + lo) * 128 + g * 8);
        s[f] = __builtin_amdgcn_mfma_f32_16x16x32_bf16(
            kf, qf, f32x4{0.f, 0.f, 0.f, 0.f}, 0, 0, 0);
    }

    float mx = -1e30f;
#pragma unroll
    for (int f = 0; f < 16; ++f) {
        const f32x4 mk = *(const f32x4*)&mb[f * 16 + g * 4];
#pragma unroll
        for (int r = 0; r < 4; ++r) {
            s[f][r] = s[f][r] * kScale + mk[r];
            mx = fmaxf(mx, s[f][r]);
        }
    }
    mx = fmaxf(mx, __shfl_xor(mx, 16, 64));
    mx = fmaxf(mx, __shfl_xor(mx, 32, 64));

    float ls = 0.f;
#pragma unroll
    for (int f = 0; f < 16; ++f)
#pragma unroll
        for (int r = 0; r < 4; ++r) {
            const float p = __expf(s[f][r] - mx);
            s[f][r] = p;
            ls += p;
        }
    ls += __shfl_xor(ls, 16, 64);
    ls += __shfl_xor(ls, 32, 64);

    if constexpr (WEIGHTS) {
        if (strip == 3 && w == 3 && lo == 15) {
            const float inv = 1.f / ls;
            float* wrow = wout + ((size_t)b * 4 + h) * 256;
#pragma unroll
            for (int f = 0; f < 16; ++f)
#pragma unroll
                for (int r = 0; r < 4; ++r)
                    wrow[f * 16 + g * 4 + r] = s[f][r] * inv;
        }
        if (blockIdx.x == 0 && t == 0) l1out[0] = 1024.0f;
    }

    // P -> LDS, XOR-swizzled 16B chunks: elem e = f*16+4g+2pr, chunk = e>>3
#pragma unroll
    for (int f = 0; f < 16; ++f)
#pragma unroll
        for (int pr = 0; pr < 2; ++pr) {
            bf16x2 pk;
            pk[0] = (__bf16)s[f][2 * pr];
            pk[1] = (__bf16)s[f][2 * pr + 1];
            const int e = f * 16 + 4 * g + 2 * pr;
            const int addr = lo * 256 + (((e >> 3) ^ (lo & 7)) << 3) + (e & 7);
            *(bf16x2*)&Pl[w][addr] = pk;
        }
    __syncthreads();

    f32x4 o[2] = {f32x4{0.f, 0.f, 0.f, 0.f}, f32x4{0.f, 0.f, 0.f, 0.f}};
#pragma unroll
    for (int ks = 0; ks < 8; ++ks) {
        const int cc = ks * 4 + g;
        const bf16x8 pa = *(const bf16x8*)&Pl[w][lo * 256 + ((cc ^ (lo & 7)) << 3)];
#pragma unroll
        for (int nf = 0; nf < 2; ++nf) {
            const bf16x8 bv = *(const bf16x8*)&Vt[nf * 16 + lo][ks * 32 + g * 8];
            o[nf] = __builtin_amdgcn_mfma_f32_16x16x32_bf16(pa, bv, o[nf], 0, 0, 0);
        }
    }

#pragma unroll
    for (int r = 0; r < 4; ++r) {
        const float inv = 1.f / __shfl(ls, 4 * g + r, 64);
        const size_t q = q0 + g * 4 + r;
#pragma unroll
        for (int nf = 0; nf < 2; ++nf)
            ctx[base + q * 128 + nf * 16 + lo] = (__bf16)(o[nf][r] * inv);
    }
}

// ---------------------------------------------------------------------------
// O-projection + residual + LayerNorm1 -> O1 (bf16). LDS-staged (64KB),
// 512 threads / 8 waves, wave = 16 rows. (round-3 known-good)
// ---------------------------------------------------------------------------
__global__ __launch_bounds__(512) void oproj_ln(
    const __bf16* __restrict__ A, const __bf16* __restrict__ Wt,
    const float* __restrict__ bias, const float* __restrict__ resid,
    const float* __restrict__ gamma, const float* __restrict__ beta,
    __bf16* __restrict__ out)
{
    __shared__ __bf16 As[128 * 128];
    __shared__ __bf16 Ws[128 * 128];

    const int t = threadIdx.x;
    const int w = t >> 6, l = t & 63, lo = l & 15, g = l >> 4;
    const size_t m0 = (size_t)blockIdx.x * 128;

#pragma unroll
    for (int p = 0; p < 4; ++p) {
        const int ci = p * 512 + t;
        const int row = ci >> 4, c = ci & 15;
        const int cs = (c ^ (row & 7)) * 8;
        *(bf16x8*)&As[row * 128 + cs] =
            *(const bf16x8*)(A + (m0 + row) * 128 + c * 8);
        *(bf16x8*)&Ws[row * 128 + cs] =
            *(const bf16x8*)(Wt + row * 128 + c * 8);
    }
    __syncthreads();

    f32x4 acc[8];
#pragma unroll
    for (int ni = 0; ni < 8; ++ni) acc[ni] = f32x4{0.f, 0.f, 0.f, 0.f};

#pragma unroll
    for (int ks = 0; ks < 4; ++ks) {
        const int arow = w * 16 + lo;
        const bf16x8 av =
            *(const bf16x8*)&As[arow * 128 + ((g + 4 * ks) ^ (arow & 7)) * 8];
#pragma unroll
        for (int ni = 0; ni < 8; ++ni) {
            const int brow = ni * 16 + lo;
            const bf16x8 bv8 =
                *(const bf16x8*)&Ws[brow * 128 + ((g + 4 * ks) ^ (brow & 7)) * 8];
            acc[ni] = __builtin_amdgcn_mfma_f32_16x16x32_bf16(av, bv8, acc[ni], 0, 0, 0);
        }
    }

    float bcol[8], ga[8], be[8];
#pragma unroll
    for (int ni = 0; ni < 8; ++ni) {
        bcol[ni] = bias[ni * 16 + lo];
        ga[ni] = gamma[ni * 16 + lo];
        be[ni] = beta[ni * 16 + lo];
    }

    float vv[4][8];
    float s[4] = {0, 0, 0, 0}, s2[4] = {0, 0, 0, 0};
#pragma unroll
    for (int r = 0; r < 4; ++r) {
        const size_t mm = m0 + w * 16 + g * 4 + r;
#pragma unroll
        for (int ni = 0; ni < 8; ++ni) {
            const float x = acc[ni][r] + bcol[ni] + resid[mm * 128 + ni * 16 + lo];
            vv[r][ni] = x; s[r] += x; s2[r] += x * x;
        }
    }
#pragma unroll
    for (int r = 0; r < 4; ++r)
#pragma unroll
        for (int o = 1; o < 16; o <<= 1) {
            s[r] += __shfl_xor(s[r], o, 64);
            s2[r] += __shfl_xor(s2[r], o, 64);
        }
#pragma unroll
    for (int r = 0; r < 4; ++r) {
        const float mu = s[r] * (1.f / 128.f);
        const float var = s2[r] * (1.f / 128.f) - mu * mu;
        const float rs = rsqrtf(var + kEps);
        const size_t mm = m0 + w * 16 + g * 4 + r;
#pragma unroll
        for (int ni = 0; ni < 8; ++ni)
            out[mm * 128 + ni * 16 + lo] =
                (__bf16)(ga[ni] * (vv[r][ni] - mu) * rs + be[ni]);
    }
}

// ---------------------------------------------------------------------------
// Tree aggregation (perfect binary tree, 255 nodes) + y = out1 + tab (bf16 IO,
// f32 LDS). Block = (b, 32-feature chunk), 32KB LDS. (round-3 known-good)
// ---------------------------------------------------------------------------
__global__ __launch_bounds__(256) void tree_agg(
    const __bf16* __restrict__ o1, __bf16* __restrict__ y)
{
    __shared__ float e[255 * 32];
    const int b = blockIdx.x;
    const int f0 = blockIdx.y * 32;
    const int t = threadIdx.x;
    const __bf16* xb = o1 + (size_t)b * 256 * 128 + f0;

#pragma unroll
    for (int p = 0; p < 4; ++p) {
        const int vidx = p * 256 + t;
        if (vidx < 1020) {
            const int n = vidx >> 2, f8 = (vidx & 3) * 8;
            const bf16x8 v = *(const bf16x8*)(xb + (size_t)n * 128 + f8);
#pragma unroll
            for (int i = 0; i < 8; ++i) e[n * 32 + f8 + i] = (float)v[i];
        }
    }
    __syncthreads();

    for (int lvl = 6; lvl >= 0; --lvl) {
        const int p0 = (1 << lvl) - 1;
        const int total = (1 << lvl) * 32;
        for (int wk = t; wk < total; wk += 256) {
            const int p = p0 + (wk >> 5), f = wk & 31;
            e[p * 32 + f] = tanhf(e[(2 * p + 1) * 32 + f] + e[(2 * p + 2) * 32 + f]);
        }
        __syncthreads();
    }

    __bf16* yb = y + (size_t)b * 256 * 128 + f0;
#pragma unroll
    for (int p = 0; p < 4; ++p) {
        const int vidx = p * 256 + t;
        const int n = vidx >> 2, f8 = (vidx & 3) * 8;
        const bf16x8 v = *(const bf16x8*)(xb + (size_t)n * 128 + f8);
        bf16x8 o;
#pragma unroll
        for (int i = 0; i < 8; ++i) {
            const float ov = (float)v[i];
            const float tab = (n < 255) ? e[n * 32 + f8 + i] : ov;
            o[i] = (__bf16)(ov + tab);
        }
        *(bf16x8*)(yb + (size_t)n * 128 + f8) = o;
    }
}

// ---------------------------------------------------------------------------
// LayerNorm over 128 cols: one wave per row, bf16 in, f32 out (= next x).
// ---------------------------------------------------------------------------
__global__ __launch_bounds__(256) void ln128(
    const __bf16* __restrict__ y, const float* __restrict__ gamma,
    const float* __restrict__ beta, float* __restrict__ xo)
{
    const int row = blockIdx.x * 4 + (threadIdx.x >> 6);
    const int lane = threadIdx.x & 63;
    const bf16x2 v = *(const bf16x2*)(y + (size_t)row * 128 + lane * 2);
    const float vx = (float)v[0], vy = (float)v[1];
    float s = vx + vy, s2 = vx * vx + vy * vy;
#pragma unroll
    for (int o = 1; o < 64; o <<= 1) {
        s += __shfl_xor(s, o, 64);
        s2 += __shfl_xor(s2, o, 64);
    }
    const float mu = s * (1.f / 128.f);
    const float var = s2 * (1.f / 128.f) - mu * mu;
    const float rs = rsqrtf(var + kEps);
    const float2 gv = *(const float2*)(gamma + lane * 2);
    const float2 bb = *(const float2*)(beta + lane * 2);
    float2 o2;
    o2.x = gv.x * (vx - mu) * rs + bb.x;
    o2.y = gv.y * (vy - mu) * rs + bb.y;
    *(float2*)(xo + (size_t)row * 128 + lane * 2) = o2;
}

// ---------------------------------------------------------------------------
extern "C" void kernel_launch(void* const* d_in, const int* in_sizes, int n_in,
                              void* d_out, int out_size, void* d_ws, size_t ws_size,
                              hipStream_t stream)
{
    (void)in_sizes; (void)n_in; (void)out_size; (void)ws_size;

    const float* x_in = (const float*)d_in[0];
    const float* mask = (const float*)d_in[1];
    const float* Wq = (const float*)d_in[5];
    const float* bq = (const float*)d_in[6];
    const float* Wk = (const float*)d_in[7];
    const float* bk = (const float*)d_in[8];
    const float* Wv = (const float*)d_in[9];
    const float* bv = (const float*)d_in[10];
    const float* Wo = (const float*)d_in[11];
    const float* bo = (const float*)d_in[12];
    const float* g1 = (const float*)d_in[13];
    const float* b1 = (const float*)d_in[14];
    const float* g2 = (const float*)d_in[15];
    const float* b2 = (const float*)d_in[16];

    float* out_x = (float*)d_out;
    float* out_l1 = out_x + kSZ;
    float* out_w = out_l1 + 1;

    char* wsb = (char*)d_ws;
    __bf16* Qb = (__bf16*)wsb;
    __bf16* Kb = (__bf16*)(wsb + 1 * kSZ * 2);
    __bf16* Vb = (__bf16*)(wsb + 2 * kSZ * 2);
    __bf16* CX = (__bf16*)(wsb + 3 * kSZ * 2);
    __bf16* O1 = (__bf16*)(wsb + 4 * kSZ * 2);
    __bf16* Y  = (__bf16*)(wsb + 5 * kSZ * 2);
    __bf16* Wt = (__bf16*)(wsb + 6 * kSZ * 2);   // 8 * 16384 bf16

    wtrans<<<8, 256, 0, stream>>>(Wq, Wk, Wv, Wo, Wt);

    for (int l = 0; l < 2; ++l) {
        const float* xi = (l == 0) ? x_in : out_x;  // f32 A + residual source
        const __bf16* WtL = Wt + (size_t)l * 4 * kD * kD;
        const size_t bof = (size_t)l * kD;

        qkv_gemm<<<256, 512, 0, stream>>>(xi, WtL, bq + bof, bk + bof, bv + bof,
                                          Qb, Kb, Vb);

        if (l == 0)
            attn_mfma<0><<<2048, 256, 0, stream>>>(Qb, Kb, Vb, mask, CX,
                                                   nullptr, nullptr);
        else
            attn_mfma<1><<<2048, 256, 0, stream>>>(Qb, Kb, Vb, mask, CX,
                                                   out_w, out_l1);

        oproj_ln<<<256, 512, 0, stream>>>(CX, WtL + 3 * kD * kD, bo + bof, xi,
                                          g1 + bof, b1 + bof, O1);

        tree_agg<<<dim3(kB, 4), 256, 0, stream>>>(O1, Y);
        ln128<<<kB * kS / 4, 256, 0, stream>>>(Y, g2 + bof, b2 + bof, out_x);
    }
}

// Round 6
// 136.976 us; speedup vs baseline: 1.7403x; 1.2381x over previous
//
#include <hip/hip_runtime.h>
#include <math.h>

typedef __bf16 bf16x8 __attribute__((ext_vector_type(8)));
typedef __bf16 bf16x2 __attribute__((ext_vector_type(2)));
typedef float f32x4 __attribute__((ext_vector_type(4)));

namespace {
constexpr int kB = 128, kS = 256, kD = 128, kH = 4;
constexpr float kEps = 1e-6f;
constexpr float kScale = 0.17677669529663687f;  // 1/sqrt(32)
constexpr float kNeg = -1000000000.0f;
constexpr size_t kSZ = (size_t)kB * kS * kD;    // 4,194,304
}

// ---------------------------------------------------------------------------
// Weight transpose + convert: Wt[l*4+mtx][n][k] = (bf16) W[l][k][n]
// ---------------------------------------------------------------------------
__global__ __launch_bounds__(256) void wtrans(
    const float* __restrict__ Wq, const float* __restrict__ Wk,
    const float* __restrict__ Wv, const float* __restrict__ Wo,
    __bf16* __restrict__ Wt)
{
    const int mtx = blockIdx.x & 3, l = blockIdx.x >> 2;
    const float* W = (mtx == 0 ? Wq : mtx == 1 ? Wk : mtx == 2 ? Wv : Wo) +
                     (size_t)l * kD * kD;
    __bf16* o = Wt + (size_t)blockIdx.x * kD * kD;
    for (int idx = threadIdx.x; idx < kD * kD; idx += 256) {
        const int k = idx >> 7, n = idx & 127;
        o[n * 128 + k] = (__bf16)W[idx];
    }
}

// ---------------------------------------------------------------------------
// Fused QKV GEMM, 64KB LDS: A tile + ONE W tile re-staged for each of Q,K,V.
// (round-5 known-good)
// ---------------------------------------------------------------------------
__global__ __launch_bounds__(512, 4) void qkv_gemm(
    const float* __restrict__ A, const __bf16* __restrict__ Wt,
    const float* __restrict__ bq, const float* __restrict__ bk,
    const float* __restrict__ bv, __bf16* __restrict__ Qb,
    __bf16* __restrict__ Kb, __bf16* __restrict__ Vb)
{
    __shared__ __bf16 As[128 * 128];
    __shared__ __bf16 Ws[128 * 128];

    const int t = threadIdx.x;
    const int w = t >> 6, l = t & 63, lo = l & 15, g = l >> 4;
    const size_t m0 = (size_t)blockIdx.x * 128;

#pragma unroll
    for (int p = 0; p < 4; ++p) {
        const int ci = p * 512 + t;
        const int row = ci >> 4, c = ci & 15;
        const float* src = A + (m0 + row) * 128 + c * 8;
        const float4 a0 = *(const float4*)src;
        const float4 a1 = *(const float4*)(src + 4);
        bf16x8 o;
        o[0] = (__bf16)a0.x; o[1] = (__bf16)a0.y; o[2] = (__bf16)a0.z; o[3] = (__bf16)a0.w;
        o[4] = (__bf16)a1.x; o[5] = (__bf16)a1.y; o[6] = (__bf16)a1.z; o[7] = (__bf16)a1.w;
        *(bf16x8*)&As[row * 128 + (c ^ (row & 7)) * 8] = o;
    }
#pragma unroll
    for (int p = 0; p < 4; ++p) {
        const int ci = p * 512 + t;
        const int row = ci >> 4, c = ci & 15;
        *(bf16x8*)&Ws[row * 128 + (c ^ (row & 7)) * 8] =
            *(const bf16x8*)(Wt + row * 128 + c * 8);
    }
    __syncthreads();

    bf16x8 av[4];
    {
        const int arow = w * 16 + lo;
#pragma unroll
        for (int ks = 0; ks < 4; ++ks)
            av[ks] = *(const bf16x8*)&As[arow * 128 + ((g + 4 * ks) ^ (arow & 7)) * 8];
    }

    const float* biases[3] = {bq, bk, bv};
    __bf16* outs[3] = {Qb, Kb, Vb};

#pragma unroll
    for (int m = 0; m < 3; ++m) {
        f32x4 acc[8];
#pragma unroll
        for (int ni = 0; ni < 8; ++ni) acc[ni] = f32x4{0.f, 0.f, 0.f, 0.f};
#pragma unroll
        for (int ks = 0; ks < 4; ++ks)
#pragma unroll
            for (int ni = 0; ni < 8; ++ni) {
                const int brow = ni * 16 + lo;
                const bf16x8 bv8 =
                    *(const bf16x8*)&Ws[brow * 128 + ((g + 4 * ks) ^ (brow & 7)) * 8];
                acc[ni] = __builtin_amdgcn_mfma_f32_16x16x32_bf16(av[ks], bv8, acc[ni], 0, 0, 0);
            }
#pragma unroll
        for (int ni = 0; ni < 8; ++ni) {
            const float bc = biases[m][ni * 16 + lo];
#pragma unroll
            for (int r = 0; r < 4; ++r)
                outs[m][(m0 + w * 16 + g * 4 + r) * 128 + ni * 16 + lo] =
                    (__bf16)(acc[ni][r] + bc);
        }
        if (m < 2) {
            __syncthreads();
#pragma unroll
            for (int p = 0; p < 4; ++p) {
                const int ci = p * 512 + t;
                const int row = ci >> 4, c = ci & 15;
                *(bf16x8*)&Ws[row * 128 + (c ^ (row & 7)) * 8] =
                    *(const bf16x8*)(Wt + (m + 1) * 16384 + row * 128 + c * 8);
            }
            __syncthreads();
        }
    }
}

// ---------------------------------------------------------------------------
// FUSED attention + O-projection + residual + LayerNorm1.
// Grid 256 = (b, qstrip of 128); 512 threads = 8 waves x 16 queries.
// Per head: stage K_h (swizzled [256][32]) + V_h^T (stride 270) -> QK^T MFMA
// -> full softmax in regs -> half-P LDS -> PV MFMA -> normalized ctx into
// swizzled LDS tile. After 4 heads: O-proj from ctx-LDS with LDS-staged Wo,
// fused bias+residual+LN1 -> O1 (bf16). ~130KB LDS, 1 block/CU, no tail.
// WEIGHTS: wave holding q=255 (strip1,w7,lo15) emits softmax rows per head;
// total_l1 = L*B*H = 1024 exactly (softmax rows positive, sum to 1).
// ---------------------------------------------------------------------------
template <int WEIGHTS>
__global__ __launch_bounds__(512) void attn_oproj(
    const __bf16* __restrict__ Qb, const __bf16* __restrict__ Kb,
    const __bf16* __restrict__ Vb, const float* __restrict__ mask,
    const __bf16* __restrict__ Wo, const float* __restrict__ bo,
    const float* __restrict__ resid, const float* __restrict__ gamma,
    const float* __restrict__ beta, __bf16* __restrict__ O1,
    float* __restrict__ wout, float* __restrict__ l1out)
{
    __shared__ __bf16 Kls[256 * 32];   // [key][32], 4 chunks/row XOR-swizzled
    __shared__ __bf16 Vt[32][270];     // V^T [d][key], stride 270
    __shared__ __bf16 Pl[8][16 * 128]; // per-wave half-P, 16 chunks/row swz
    __shared__ __bf16 Ctx[128 * 128];  // swizzled ctx tile
    __shared__ __bf16 Wos[128 * 128];  // swizzled Wo
    __shared__ float mb[256];

    const int t = threadIdx.x;
    const int w = t >> 6, l = t & 63, lo = l & 15, g = l >> 4;
    const int b = blockIdx.x >> 1, strip = blockIdx.x & 1;
    const size_t bbase = (size_t)b * 256 * 128;
    const int q0 = strip * 128 + w * 16;       // batch-local first q of wave
    const int kswz = (lo ^ (lo >> 2)) & 3;     // K-frag chunk swizzle (per lane)

    // stage Wo once (swizzled, same pattern as GEMM Ws)
#pragma unroll
    for (int p = 0; p < 4; ++p) {
        const int ci = p * 512 + t;
        const int row = ci >> 4, c = ci & 15;
        *(bf16x8*)&Wos[row * 128 + ((c ^ (row & 7)) << 3)] =
            *(const bf16x8*)(Wo + row * 128 + c * 8);
    }
    if (t < 256) mb[t] = mask[b * 256 + t] * kNeg;
    if (WEIGHTS && blockIdx.x == 0 && t == 0) l1out[0] = 1024.0f;

    // K/V staging for head h
    auto stageKV = [&](int h) {
#pragma unroll
        for (int p = 0; p < 2; ++p) {            // 1024 K-chunks
            const int ci = p * 512 + t;
            const int row = ci >> 2, c = ci & 3;
            const int sw = (c ^ ((row ^ (row >> 2)) & 3)) << 3;
            *(bf16x8*)&Kls[row * 32 + sw] =
                *(const bf16x8*)(Kb + bbase + (size_t)row * 128 + h * 32 + c * 8);
        }
#pragma unroll
        for (int p = 0; p < 2; ++p) {            // V^T scatter
            const int key = p * 128 + (t >> 2);
            const int d0 = (t & 3) << 3;
            const bf16x8 v = *(const bf16x8*)(Vb + bbase + (size_t)key * 128 + h * 32 + d0);
#pragma unroll
            for (int i = 0; i < 8; ++i) Vt[d0 + i][key] = v[i];
        }
    };

    stageKV(0);
    __syncthreads();

    for (int h = 0; h < 4; ++h) {
        // Q fragment for this head (global, L2-hot)
        const bf16x8 qf =
            *(const bf16x8*)(Qb + bbase + (size_t)(q0 + lo) * 128 + h * 32 + g * 8);

        // S^T = K @ Q^T  (16 key-frags)
        f32x4 s[16];
#pragma unroll
        for (int f = 0; f < 16; ++f) {
            const bf16x8 kf =
                *(const bf16x8*)&Kls[(f * 16 + lo) * 32 + ((g ^ kswz) << 3)];
            s[f] = __builtin_amdgcn_mfma_f32_16x16x32_bf16(
                kf, qf, f32x4{0.f, 0.f, 0.f, 0.f}, 0, 0, 0);
        }

        // scale + mask; column (q) max over in-lane 64 + cross-lane 16/32
        float mx = -1e30f;
#pragma unroll
        for (int f = 0; f < 16; ++f) {
            const f32x4 mk = *(const f32x4*)&mb[f * 16 + g * 4];
#pragma unroll
            for (int r = 0; r < 4; ++r) {
                s[f][r] = s[f][r] * kScale + mk[r];
                mx = fmaxf(mx, s[f][r]);
            }
        }
        mx = fmaxf(mx, __shfl_xor(mx, 16, 64));
        mx = fmaxf(mx, __shfl_xor(mx, 32, 64));

        float ls = 0.f;
#pragma unroll
        for (int f = 0; f < 16; ++f)
#pragma unroll
            for (int r = 0; r < 4; ++r) {
                const float p = __expf(s[f][r] - mx);
                s[f][r] = p;
                ls += p;
            }
        ls += __shfl_xor(ls, 16, 64);
        ls += __shfl_xor(ls, 32, 64);

        if constexpr (WEIGHTS) {
            // q=255: strip 1, wave 7, lo 15 (all 4 g-lanes hold 64 keys each)
            if (strip == 1 && w == 7 && lo == 15) {
                const float inv = 1.f / ls;
                float* wrow = wout + ((size_t)b * 4 + h) * 256;
#pragma unroll
                for (int f = 0; f < 16; ++f)
#pragma unroll
                    for (int r = 0; r < 4; ++r)
                        wrow[f * 16 + g * 4 + r] = s[f][r] * inv;
            }
        }

        // PV in two half-P passes (keys 0..127, 128..255)
        f32x4 o[2] = {f32x4{0.f, 0.f, 0.f, 0.f}, f32x4{0.f, 0.f, 0.f, 0.f}};
#pragma unroll
        for (int half = 0; half < 2; ++half) {
#pragma unroll
            for (int f = 0; f < 8; ++f) {
                const int ff = half * 8 + f;
#pragma unroll
                for (int pr = 0; pr < 2; ++pr) {
                    bf16x2 pk;
                    pk[0] = (__bf16)s[ff][2 * pr];
                    pk[1] = (__bf16)s[ff][2 * pr + 1];
                    const int e = f * 16 + 4 * g + 2 * pr;  // 0..127
                    const int addr =
                        lo * 128 + ((((e >> 3) ^ (lo & 7)) << 3) | (e & 7));
                    *(bf16x2*)&Pl[w][addr] = pk;
                }
            }
#pragma unroll
            for (int ks = 0; ks < 4; ++ks) {
                const int cc = ks * 4 + g;
                const bf16x8 pa =
                    *(const bf16x8*)&Pl[w][lo * 128 + ((cc ^ (lo & 7)) << 3)];
#pragma unroll
                for (int nf = 0; nf < 2; ++nf) {
                    const bf16x8 bv =
                        *(const bf16x8*)&Vt[nf * 16 + lo][(half * 4 + ks) * 32 + g * 8];
                    o[nf] = __builtin_amdgcn_mfma_f32_16x16x32_bf16(pa, bv, o[nf], 0, 0, 0);
                }
            }
        }

        // normalized ctx -> swizzled LDS tile (cols h*32..h*32+31)
#pragma unroll
        for (int r = 0; r < 4; ++r) {
            const float inv = 1.f / __shfl(ls, 4 * g + r, 64);
            const int crow = w * 16 + g * 4 + r;
#pragma unroll
            for (int nf = 0; nf < 2; ++nf) {
                const int col = h * 32 + nf * 16 + lo;
                const int chunk = (col >> 3) ^ (crow & 7);
                Ctx[crow * 128 + (chunk << 3) + (col & 7)] = (__bf16)(o[nf][r] * inv);
            }
        }
        __syncthreads();          // ctx writes done; K/V free to restage
        if (h < 3) {
            stageKV(h + 1);
            __syncthreads();
        }
    }

    // ---- O-projection + residual + LN1 (wave = 16 rows) ----
    const size_t m0 = (size_t)b * 256 + strip * 128;
    f32x4 acc[8];
#pragma unroll
    for (int ni = 0; ni < 8; ++ni) acc[ni] = f32x4{0.f, 0.f, 0.f, 0.f};

    const int arow = w * 16 + lo;
#pragma unroll
    for (int ks = 0; ks < 4; ++ks) {
        const bf16x8 av =
            *(const bf16x8*)&Ctx[arow * 128 + (((g + 4 * ks) ^ (arow & 7)) << 3)];
#pragma unroll
        for (int ni = 0; ni < 8; ++ni) {
            const int brow = ni * 16 + lo;
            const bf16x8 bv8 =
                *(const bf16x8*)&Wos[brow * 128 + (((g + 4 * ks) ^ (brow & 7)) << 3)];
            acc[ni] = __builtin_amdgcn_mfma_f32_16x16x32_bf16(av, bv8, acc[ni], 0, 0, 0);
        }
    }

    float bcol[8], ga[8], be[8];
#pragma unroll
    for (int ni = 0; ni < 8; ++ni) {
        bcol[ni] = bo[ni * 16 + lo];
        ga[ni] = gamma[ni * 16 + lo];
        be[ni] = beta[ni * 16 + lo];
    }

    float vv[4][8];
    float s[4] = {0, 0, 0, 0}, s2[4] = {0, 0, 0, 0};
#pragma unroll
    for (int r = 0; r < 4; ++r) {
        const size_t mm = m0 + w * 16 + g * 4 + r;
#pragma unroll
        for (int ni = 0; ni < 8; ++ni) {
            const float x = acc[ni][r] + bcol[ni] + resid[mm * 128 + ni * 16 + lo];
            vv[r][ni] = x; s[r] += x; s2[r] += x * x;
        }
    }
#pragma unroll
    for (int r = 0; r < 4; ++r)
#pragma unroll
        for (int o = 1; o < 16; o <<= 1) {
            s[r] += __shfl_xor(s[r], o, 64);
            s2[r] += __shfl_xor(s2[r], o, 64);
        }
#pragma unroll
    for (int r = 0; r < 4; ++r) {
        const float mu = s[r] * (1.f / 128.f);
        const float var = s2[r] * (1.f / 128.f) - mu * mu;
        const float rs = rsqrtf(var + kEps);
        const size_t mm = m0 + w * 16 + g * 4 + r;
#pragma unroll
        for (int ni = 0; ni < 8; ++ni)
            O1[mm * 128 + ni * 16 + lo] =
                (__bf16)(ga[ni] * (vv[r][ni] - mu) * rs + be[ni]);
    }
}

// ---------------------------------------------------------------------------
// Tree aggregation (perfect binary tree, 255 nodes) + y = out1 + tab
// (round-3 known-good)
// ---------------------------------------------------------------------------
__global__ __launch_bounds__(256) void tree_agg(
    const __bf16* __restrict__ o1, __bf16* __restrict__ y)
{
    __shared__ float e[255 * 32];
    const int b = blockIdx.x;
    const int f0 = blockIdx.y * 32;
    const int t = threadIdx.x;
    const __bf16* xb = o1 + (size_t)b * 256 * 128 + f0;

#pragma unroll
    for (int p = 0; p < 4; ++p) {
        const int vidx = p * 256 + t;
        if (vidx < 1020) {
            const int n = vidx >> 2, f8 = (vidx & 3) * 8;
            const bf16x8 v = *(const bf16x8*)(xb + (size_t)n * 128 + f8);
#pragma unroll
            for (int i = 0; i < 8; ++i) e[n * 32 + f8 + i] = (float)v[i];
        }
    }
    __syncthreads();

    for (int lvl = 6; lvl >= 0; --lvl) {
        const int p0 = (1 << lvl) - 1;
        const int total = (1 << lvl) * 32;
        for (int wk = t; wk < total; wk += 256) {
            const int p = p0 + (wk >> 5), f = wk & 31;
            e[p * 32 + f] = tanhf(e[(2 * p + 1) * 32 + f] + e[(2 * p + 2) * 32 + f]);
        }
        __syncthreads();
    }

    __bf16* yb = y + (size_t)b * 256 * 128 + f0;
#pragma unroll
    for (int p = 0; p < 4; ++p) {
        const int vidx = p * 256 + t;
        const int n = vidx >> 2, f8 = (vidx & 3) * 8;
        const bf16x8 v = *(const bf16x8*)(xb + (size_t)n * 128 + f8);
        bf16x8 o;
#pragma unroll
        for (int i = 0; i < 8; ++i) {
            const float ov = (float)v[i];
            const float tab = (n < 255) ? e[n * 32 + f8 + i] : ov;
            o[i] = (__bf16)(ov + tab);
        }
        *(bf16x8*)(yb + (size_t)n * 128 + f8) = o;
    }
}

// ---------------------------------------------------------------------------
// LayerNorm over 128 cols: one wave per row, bf16 in, f32 out (= next x).
// ---------------------------------------------------------------------------
__global__ __launch_bounds__(256) void ln128(
    const __bf16* __restrict__ y, const float* __restrict__ gamma,
    const float* __restrict__ beta, float* __restrict__ xo)
{
    const int row = blockIdx.x * 4 + (threadIdx.x >> 6);
    const int lane = threadIdx.x & 63;
    const bf16x2 v = *(const bf16x2*)(y + (size_t)row * 128 + lane * 2);
    const float vx = (float)v[0], vy = (float)v[1];
    float s = vx + vy, s2 = vx * vx + vy * vy;
#pragma unroll
    for (int o = 1; o < 64; o <<= 1) {
        s += __shfl_xor(s, o, 64);
        s2 += __shfl_xor(s2, o, 64);
    }
    const float mu = s * (1.f / 128.f);
    const float var = s2 * (1.f / 128.f) - mu * mu;
    const float rs = rsqrtf(var + kEps);
    const float2 gv = *(const float2*)(gamma + lane * 2);
    const float2 bb = *(const float2*)(beta + lane * 2);
    float2 o2;
    o2.x = gv.x * (vx - mu) * rs + bb.x;
    o2.y = gv.y * (vy - mu) * rs + bb.y;
    *(float2*)(xo + (size_t)row * 128 + lane * 2) = o2;
}

// ---------------------------------------------------------------------------
extern "C" void kernel_launch(void* const* d_in, const int* in_sizes, int n_in,
                              void* d_out, int out_size, void* d_ws, size_t ws_size,
                              hipStream_t stream)
{
    (void)in_sizes; (void)n_in; (void)out_size; (void)ws_size;

    const float* x_in = (const float*)d_in[0];
    const float* mask = (const float*)d_in[1];
    const float* Wq = (const float*)d_in[5];
    const float* bq = (const float*)d_in[6];
    const float* Wk = (const float*)d_in[7];
    const float* bk = (const float*)d_in[8];
    const float* Wv = (const float*)d_in[9];
    const float* bv = (const float*)d_in[10];
    const float* Wo = (const float*)d_in[11];
    const float* bo = (const float*)d_in[12];
    const float* g1 = (const float*)d_in[13];
    const float* b1 = (const float*)d_in[14];
    const float* g2 = (const float*)d_in[15];
    const float* b2 = (const float*)d_in[16];

    float* out_x = (float*)d_out;
    float* out_l1 = out_x + kSZ;
    float* out_w = out_l1 + 1;

    char* wsb = (char*)d_ws;
    __bf16* Qb = (__bf16*)wsb;
    __bf16* Kb = (__bf16*)(wsb + 1 * kSZ * 2);
    __bf16* Vb = (__bf16*)(wsb + 2 * kSZ * 2);
    __bf16* O1 = (__bf16*)(wsb + 3 * kSZ * 2);
    __bf16* Y  = (__bf16*)(wsb + 4 * kSZ * 2);
    __bf16* Wt = (__bf16*)(wsb + 5 * kSZ * 2);   // 8 * 16384 bf16

    wtrans<<<8, 256, 0, stream>>>(Wq, Wk, Wv, Wo, Wt);

    for (int l = 0; l < 2; ++l) {
        const float* xi = (l == 0) ? x_in : out_x;  // f32 A + residual source
        const __bf16* WtL = Wt + (size_t)l * 4 * kD * kD;
        const size_t bof = (size_t)l * kD;

        qkv_gemm<<<256, 512, 0, stream>>>(xi, WtL, bq + bof, bk + bof, bv + bof,
                                          Qb, Kb, Vb);

        if (l == 0)
            attn_oproj<0><<<256, 512, 0, stream>>>(Qb, Kb, Vb, mask,
                                                   WtL + 3 * kD * kD, bo + bof,
                                                   xi, g1 + bof, b1 + bof, O1,
                                                   nullptr, nullptr);
        else
            attn_oproj<1><<<256, 512, 0, stream>>>(Qb, Kb, Vb, mask,
                                                   WtL + 3 * kD * kD, bo + bof,
                                                   xi, g1 + bof, b1 + bof, O1,
                                                   out_w, out_l1);

        tree_agg<<<dim3(kB, 4), 256, 0, stream>>>(O1, Y);
        ln128<<<kB * kS / 4, 256, 0, stream>>>(Y, g2 + bof, b2 + bof, out_x);
    }
}

// Round 7
// 133.051 us; speedup vs baseline: 1.7917x; 1.0295x over previous
//
#include <hip/hip_runtime.h>
#include <math.h>

typedef __bf16 bf16x8 __attribute__((ext_vector_type(8)));
typedef __bf16 bf16x2 __attribute__((ext_vector_type(2)));
typedef float f32x4 __attribute__((ext_vector_type(4)));

namespace {
constexpr int kB = 128, kS = 256, kD = 128, kH = 4;
constexpr float kEps = 1e-6f;
constexpr float kScale = 0.17677669529663687f;  // 1/sqrt(32)
constexpr float kNeg = -1000000000.0f;
constexpr size_t kSZ = (size_t)kB * kS * kD;    // 4,194,304
}

// ---------------------------------------------------------------------------
// Weight transpose + convert: Wt[l*4+mtx][n][k] = (bf16) W[l][k][n]
// ---------------------------------------------------------------------------
__global__ __launch_bounds__(256) void wtrans(
    const float* __restrict__ Wq, const float* __restrict__ Wk,
    const float* __restrict__ Wv, const float* __restrict__ Wo,
    __bf16* __restrict__ Wt)
{
    const int mtx = blockIdx.x & 3, l = blockIdx.x >> 2;
    const float* W = (mtx == 0 ? Wq : mtx == 1 ? Wk : mtx == 2 ? Wv : Wo) +
                     (size_t)l * kD * kD;
    __bf16* o = Wt + (size_t)blockIdx.x * kD * kD;
    for (int idx = threadIdx.x; idx < kD * kD; idx += 256) {
        const int k = idx >> 7, n = idx & 127;
        o[n * 128 + k] = (__bf16)W[idx];
    }
}

// ---------------------------------------------------------------------------
// Fused QKV GEMM, 64KB LDS: A tile + ONE W tile re-staged for each of Q,K,V.
// A source is f32 (layer 0) or bf16 (layer 1). (round-5/6 known-good body)
// ---------------------------------------------------------------------------
template <bool F32A>
__global__ __launch_bounds__(512, 4) void qkv_gemm(
    const void* __restrict__ Av, const __bf16* __restrict__ Wt,
    const float* __restrict__ bq, const float* __restrict__ bk,
    const float* __restrict__ bv, __bf16* __restrict__ Qb,
    __bf16* __restrict__ Kb, __bf16* __restrict__ Vb)
{
    __shared__ __bf16 As[128 * 128];
    __shared__ __bf16 Ws[128 * 128];

    const int t = threadIdx.x;
    const int w = t >> 6, l = t & 63, lo = l & 15, g = l >> 4;
    const size_t m0 = (size_t)blockIdx.x * 128;

#pragma unroll
    for (int p = 0; p < 4; ++p) {
        const int ci = p * 512 + t;
        const int row = ci >> 4, c = ci & 15;
        if constexpr (F32A) {
            const float* src = (const float*)Av + (m0 + row) * 128 + c * 8;
            const float4 a0 = *(const float4*)src;
            const float4 a1 = *(const float4*)(src + 4);
            bf16x8 o;
            o[0] = (__bf16)a0.x; o[1] = (__bf16)a0.y; o[2] = (__bf16)a0.z; o[3] = (__bf16)a0.w;
            o[4] = (__bf16)a1.x; o[5] = (__bf16)a1.y; o[6] = (__bf16)a1.z; o[7] = (__bf16)a1.w;
            *(bf16x8*)&As[row * 128 + (c ^ (row & 7)) * 8] = o;
        } else {
            *(bf16x8*)&As[row * 128 + (c ^ (row & 7)) * 8] =
                *(const bf16x8*)((const __bf16*)Av + (m0 + row) * 128 + c * 8);
        }
    }
#pragma unroll
    for (int p = 0; p < 4; ++p) {
        const int ci = p * 512 + t;
        const int row = ci >> 4, c = ci & 15;
        *(bf16x8*)&Ws[row * 128 + (c ^ (row & 7)) * 8] =
            *(const bf16x8*)(Wt + row * 128 + c * 8);
    }
    __syncthreads();

    bf16x8 av[4];
    {
        const int arow = w * 16 + lo;
#pragma unroll
        for (int ks = 0; ks < 4; ++ks)
            av[ks] = *(const bf16x8*)&As[arow * 128 + ((g + 4 * ks) ^ (arow & 7)) * 8];
    }

    const float* biases[3] = {bq, bk, bv};
    __bf16* outs[3] = {Qb, Kb, Vb};

#pragma unroll
    for (int m = 0; m < 3; ++m) {
        f32x4 acc[8];
#pragma unroll
        for (int ni = 0; ni < 8; ++ni) acc[ni] = f32x4{0.f, 0.f, 0.f, 0.f};
#pragma unroll
        for (int ks = 0; ks < 4; ++ks)
#pragma unroll
            for (int ni = 0; ni < 8; ++ni) {
                const int brow = ni * 16 + lo;
                const bf16x8 bv8 =
                    *(const bf16x8*)&Ws[brow * 128 + ((g + 4 * ks) ^ (brow & 7)) * 8];
                acc[ni] = __builtin_amdgcn_mfma_f32_16x16x32_bf16(av[ks], bv8, acc[ni], 0, 0, 0);
            }
#pragma unroll
        for (int ni = 0; ni < 8; ++ni) {
            const float bc = biases[m][ni * 16 + lo];
#pragma unroll
            for (int r = 0; r < 4; ++r)
                outs[m][(m0 + w * 16 + g * 4 + r) * 128 + ni * 16 + lo] =
                    (__bf16)(acc[ni][r] + bc);
        }
        if (m < 2) {
            __syncthreads();
#pragma unroll
            for (int p = 0; p < 4; ++p) {
                const int ci = p * 512 + t;
                const int row = ci >> 4, c = ci & 15;
                *(bf16x8*)&Ws[row * 128 + (c ^ (row & 7)) * 8] =
                    *(const bf16x8*)(Wt + (m + 1) * 16384 + row * 128 + c * 8);
            }
            __syncthreads();
        }
    }
}

// ---------------------------------------------------------------------------
// FUSED attention + O-projection + residual + LayerNorm1.
// Grid 256 = (b, qstrip of 128); 512 threads = 8 waves x 16 queries.
// T14 async-stage: next head's K/V issued global->reg right after QK^T
// (latency hides under softmax+PV), ds-written after the ctx barrier.
// Q fragments for all 4 heads hoisted to registers up front.
// RESF32: residual source f32 (layer0) or bf16 (layer1).
// WEIGHTS: wave holding q=255 emits softmax rows; total_l1 = 1024 exactly.
// ---------------------------------------------------------------------------
template <int WEIGHTS, bool RESF32>
__global__ __launch_bounds__(512) void attn_oproj(
    const __bf16* __restrict__ Qb, const __bf16* __restrict__ Kb,
    const __bf16* __restrict__ Vb, const float* __restrict__ mask,
    const __bf16* __restrict__ Wo, const float* __restrict__ bo,
    const void* __restrict__ resid, const float* __restrict__ gamma,
    const float* __restrict__ beta, __bf16* __restrict__ O1,
    float* __restrict__ wout, float* __restrict__ l1out)
{
    __shared__ __bf16 Kls[256 * 32];   // [key][32], 4 chunks/row XOR-swizzled
    __shared__ __bf16 Vt[32][270];     // V^T [d][key]
    __shared__ __bf16 Pl[8][16 * 128]; // per-wave half-P, swizzled chunks
    __shared__ __bf16 Ctx[128 * 128];  // swizzled ctx tile
    __shared__ __bf16 Wos[128 * 128];  // swizzled Wo
    __shared__ float mb[256];

    const int t = threadIdx.x;
    const int w = t >> 6, l = t & 63, lo = l & 15, g = l >> 4;
    const int b = blockIdx.x >> 1, strip = blockIdx.x & 1;
    const size_t bbase = (size_t)b * 256 * 128;
    const int q0 = strip * 128 + w * 16;
    const int kswz = (lo ^ (lo >> 2)) & 3;

    // prefetch registers for K/V staging (T14)
    bf16x8 kpre[2], vpre[2];
    const int krow = t >> 2, kc = t & 3;          // K: 2 chunks/thread
    const int vkey = t >> 2, vd0 = (t & 3) << 3;  // V: 2 chunks/thread

    auto loadKV = [&](int h) {
#pragma unroll
        for (int p = 0; p < 2; ++p)
            kpre[p] = *(const bf16x8*)(Kb + bbase + (size_t)(p * 128 + krow) * 128 +
                                       h * 32 + kc * 8);
#pragma unroll
        for (int p = 0; p < 2; ++p)
            vpre[p] = *(const bf16x8*)(Vb + bbase + (size_t)(p * 128 + vkey) * 128 +
                                       h * 32 + vd0);
    };
    auto writeKV = [&]() {
#pragma unroll
        for (int p = 0; p < 2; ++p) {
            const int row = p * 128 + krow;
            const int sw = (kc ^ ((row ^ (row >> 2)) & 3)) << 3;
            *(bf16x8*)&Kls[row * 32 + sw] = kpre[p];
        }
#pragma unroll
        for (int p = 0; p < 2; ++p) {
            const int key = p * 128 + vkey;
#pragma unroll
            for (int i = 0; i < 8; ++i) Vt[vd0 + i][key] = vpre[p][i];
        }
    };

    // stage Wo once (swizzled)
#pragma unroll
    for (int p = 0; p < 4; ++p) {
        const int ci = p * 512 + t;
        const int row = ci >> 4, c = ci & 15;
        *(bf16x8*)&Wos[row * 128 + ((c ^ (row & 7)) << 3)] =
            *(const bf16x8*)(Wo + row * 128 + c * 8);
    }
    if (t < 256) mb[t] = mask[b * 256 + t] * kNeg;
    if (WEIGHTS && blockIdx.x == 0 && t == 0) l1out[0] = 1024.0f;

    // all 4 Q head-fragments up front
    bf16x8 qfr[4];
#pragma unroll
    for (int h = 0; h < 4; ++h)
        qfr[h] = *(const bf16x8*)(Qb + bbase + (size_t)(q0 + lo) * 128 + h * 32 + g * 8);

    loadKV(0);
    writeKV();
    __syncthreads();

#pragma unroll
    for (int h = 0; h < 4; ++h) {
        // S^T = K @ Q^T  (16 key-frags)
        f32x4 s[16];
#pragma unroll
        for (int f = 0; f < 16; ++f) {
            const bf16x8 kf =
                *(const bf16x8*)&Kls[(f * 16 + lo) * 32 + ((g ^ kswz) << 3)];
            s[f] = __builtin_amdgcn_mfma_f32_16x16x32_bf16(
                kf, qfr[h], f32x4{0.f, 0.f, 0.f, 0.f}, 0, 0, 0);
        }

        if (h < 3) loadKV(h + 1);  // T14: issue next head's K/V now

        float mx = -1e30f;
#pragma unroll
        for (int f = 0; f < 16; ++f) {
            const f32x4 mk = *(const f32x4*)&mb[f * 16 + g * 4];
#pragma unroll
            for (int r = 0; r < 4; ++r) {
                s[f][r] = s[f][r] * kScale + mk[r];
                mx = fmaxf(mx, s[f][r]);
            }
        }
        mx = fmaxf(mx, __shfl_xor(mx, 16, 64));
        mx = fmaxf(mx, __shfl_xor(mx, 32, 64));

        float ls = 0.f;
#pragma unroll
        for (int f = 0; f < 16; ++f)
#pragma unroll
            for (int r = 0; r < 4; ++r) {
                const float p = __expf(s[f][r] - mx);
                s[f][r] = p;
                ls += p;
            }
        ls += __shfl_xor(ls, 16, 64);
        ls += __shfl_xor(ls, 32, 64);

        if constexpr (WEIGHTS) {
            if (strip == 1 && w == 7 && lo == 15) {
                const float inv = 1.f / ls;
                float* wrow = wout + ((size_t)b * 4 + h) * 256;
#pragma unroll
                for (int f = 0; f < 16; ++f)
#pragma unroll
                    for (int r = 0; r < 4; ++r)
                        wrow[f * 16 + g * 4 + r] = s[f][r] * inv;
            }
        }

        // PV in two half-P passes (keys 0..127, 128..255)
        f32x4 o[2] = {f32x4{0.f, 0.f, 0.f, 0.f}, f32x4{0.f, 0.f, 0.f, 0.f}};
#pragma unroll
        for (int half = 0; half < 2; ++half) {
#pragma unroll
            for (int f = 0; f < 8; ++f) {
                const int ff = half * 8 + f;
#pragma unroll
                for (int pr = 0; pr < 2; ++pr) {
                    bf16x2 pk;
                    pk[0] = (__bf16)s[ff][2 * pr];
                    pk[1] = (__bf16)s[ff][2 * pr + 1];
                    const int e = f * 16 + 4 * g + 2 * pr;
                    const int addr =
                        lo * 128 + ((((e >> 3) ^ (lo & 7)) << 3) | (e & 7));
                    *(bf16x2*)&Pl[w][addr] = pk;
                }
            }
#pragma unroll
            for (int ks = 0; ks < 4; ++ks) {
                const int cc = ks * 4 + g;
                const bf16x8 pa =
                    *(const bf16x8*)&Pl[w][lo * 128 + ((cc ^ (lo & 7)) << 3)];
#pragma unroll
                for (int nf = 0; nf < 2; ++nf) {
                    const bf16x8 bv =
                        *(const bf16x8*)&Vt[nf * 16 + lo][(half * 4 + ks) * 32 + g * 8];
                    o[nf] = __builtin_amdgcn_mfma_f32_16x16x32_bf16(pa, bv, o[nf], 0, 0, 0);
                }
            }
        }

        // normalized ctx -> swizzled LDS tile (cols h*32..h*32+31)
#pragma unroll
        for (int r = 0; r < 4; ++r) {
            const float inv = 1.f / __shfl(ls, 4 * g + r, 64);
            const int crow = w * 16 + g * 4 + r;
#pragma unroll
            for (int nf = 0; nf < 2; ++nf) {
                const int col = h * 32 + nf * 16 + lo;
                const int chunk = (col >> 3) ^ (crow & 7);
                Ctx[crow * 128 + (chunk << 3) + (col & 7)] = (__bf16)(o[nf][r] * inv);
            }
        }
        if (h < 3) {
            __syncthreads();   // all Kls/Vt reads of head h complete
            writeKV();         // regs -> LDS for head h+1
            __syncthreads();
        }
        // (no barrier after h==3: oproj A-frags read only this wave's Ctx rows)
    }

    // ---- O-projection + residual + LN1 (wave = 16 rows) ----
    const size_t m0 = (size_t)b * 256 + strip * 128;
    f32x4 acc[8];
#pragma unroll
    for (int ni = 0; ni < 8; ++ni) acc[ni] = f32x4{0.f, 0.f, 0.f, 0.f};

    const int arow = w * 16 + lo;
#pragma unroll
    for (int ks = 0; ks < 4; ++ks) {
        const bf16x8 av =
            *(const bf16x8*)&Ctx[arow * 128 + (((g + 4 * ks) ^ (arow & 7)) << 3)];
#pragma unroll
        for (int ni = 0; ni < 8; ++ni) {
            const int brow = ni * 16 + lo;
            const bf16x8 bv8 =
                *(const bf16x8*)&Wos[brow * 128 + (((g + 4 * ks) ^ (brow & 7)) << 3)];
            acc[ni] = __builtin_amdgcn_mfma_f32_16x16x32_bf16(av, bv8, acc[ni], 0, 0, 0);
        }
    }

    float bcol[8], ga[8], be[8];
#pragma unroll
    for (int ni = 0; ni < 8; ++ni) {
        bcol[ni] = bo[ni * 16 + lo];
        ga[ni] = gamma[ni * 16 + lo];
        be[ni] = beta[ni * 16 + lo];
    }

    float vv[4][8];
    float s[4] = {0, 0, 0, 0}, s2[4] = {0, 0, 0, 0};
#pragma unroll
    for (int r = 0; r < 4; ++r) {
        const size_t mm = m0 + w * 16 + g * 4 + r;
#pragma unroll
        for (int ni = 0; ni < 8; ++ni) {
            float rv;
            if constexpr (RESF32)
                rv = ((const float*)resid)[mm * 128 + ni * 16 + lo];
            else
                rv = (float)((const __bf16*)resid)[mm * 128 + ni * 16 + lo];
            const float x = acc[ni][r] + bcol[ni] + rv;
            vv[r][ni] = x; s[r] += x; s2[r] += x * x;
        }
    }
#pragma unroll
    for (int r = 0; r < 4; ++r)
#pragma unroll
        for (int o = 1; o < 16; o <<= 1) {
            s[r] += __shfl_xor(s[r], o, 64);
            s2[r] += __shfl_xor(s2[r], o, 64);
        }
#pragma unroll
    for (int r = 0; r < 4; ++r) {
        const float mu = s[r] * (1.f / 128.f);
        const float var = s2[r] * (1.f / 128.f) - mu * mu;
        const float rs = rsqrtf(var + kEps);
        const size_t mm = m0 + w * 16 + g * 4 + r;
#pragma unroll
        for (int ni = 0; ni < 8; ++ni)
            O1[mm * 128 + ni * 16 + lo] =
                (__bf16)(ga[ni] * (vv[r][ni] - mu) * rs + be[ni]);
    }
}

// ---------------------------------------------------------------------------
// FUSED tree aggregation + residual + LayerNorm2. One block per batch.
// e[255][132] f32 in LDS (~135KB; stride 132 keeps 16B row alignment and
// cuts staging b128 write conflicts to the ~8-way structural floor).
// Residual: rows 127..254 from e (leaves unchanged); rows 0..126 and 255
// re-read from global (L2-hot). Emits f32 x and/or bf16 x per flags.
// ---------------------------------------------------------------------------
__global__ __launch_bounds__(1024) void tree_ln(
    const __bf16* __restrict__ o1, const float* __restrict__ gamma,
    const float* __restrict__ beta, float* __restrict__ xo,
    __bf16* __restrict__ xb, int wf32, int wbf16)
{
    __shared__ float e[255 * 132];
    const int b = blockIdx.x;
    const int t = threadIdx.x;
    const __bf16* ob = o1 + (size_t)b * 256 * 128;

    // stage 255 rows (4080 bf16x8 chunks) -> f32 LDS
#pragma unroll
    for (int p = 0; p < 4; ++p) {
        const int ci = p * 1024 + t;
        if (ci < 4080) {
            const int row = ci >> 4, c8 = (ci & 15) * 8;
            const bf16x8 v = *(const bf16x8*)(ob + ci * 8);
            float* dst = &e[row * 132 + c8];
#pragma unroll
            for (int i = 0; i < 8; ++i) dst[i] = (float)v[i];
        }
    }
    __syncthreads();

    // bottom-up tree: e[p] = tanh(e[2p+1] + e[2p+2])
    for (int lvl = 6; lvl >= 0; --lvl) {
        const int p0 = (1 << lvl) - 1;
        const int total = (1 << lvl) * 128;
        for (int wk = t; wk < total; wk += 1024) {
            const int p = p0 + (wk >> 7), f = wk & 127;
            e[(p)*132 + f] = tanhf(e[(2 * p + 1) * 132 + f] + e[(2 * p + 2) * 132 + f]);
        }
        __syncthreads();
    }

    // y = out1 + tab; LayerNorm per row (wave per row, 2 cols/lane)
    const int wv = t >> 6, lane = t & 63;
    const float2 gv = *(const float2*)(gamma + lane * 2);
    const float2 bb = *(const float2*)(beta + lane * 2);
    for (int row = wv; row < 256; row += 16) {
        const int c = lane * 2;
        float y0, y1;
        if (row >= 127 && row < 255) {
            // leaf rows: e holds original out1; tab == out1
            y0 = 2.f * e[row * 132 + c];
            y1 = 2.f * e[row * 132 + c + 1];
        } else if (row < 127) {
            // internal: original out1 from global, tab from (overwritten) e
            const bf16x2 v = *(const bf16x2*)(ob + (size_t)row * 128 + c);
            y0 = (float)v[0] + e[row * 132 + c];
            y1 = (float)v[1] + e[row * 132 + c + 1];
        } else {  // row == 255: pass-through, tab == out1
            const bf16x2 v = *(const bf16x2*)(ob + (size_t)row * 128 + c);
            y0 = 2.f * (float)v[0];
            y1 = 2.f * (float)v[1];
        }
        float s = y0 + y1, s2 = y0 * y0 + y1 * y1;
#pragma unroll
        for (int o = 1; o < 64; o <<= 1) {
            s += __shfl_xor(s, o, 64);
            s2 += __shfl_xor(s2, o, 64);
        }
        const float mu = s * (1.f / 128.f);
        const float var = s2 * (1.f / 128.f) - mu * mu;
        const float rs = rsqrtf(var + kEps);
        const float r0 = gv.x * (y0 - mu) * rs + bb.x;
        const float r1 = gv.y * (y1 - mu) * rs + bb.y;
        const size_t off = ((size_t)b * 256 + row) * 128 + c;
        if (wf32) {
            float2 o2; o2.x = r0; o2.y = r1;
            *(float2*)(xo + off) = o2;
        }
        if (wbf16) {
            bf16x2 ob2; ob2[0] = (__bf16)r0; ob2[1] = (__bf16)r1;
            *(bf16x2*)(xb + off) = ob2;
        }
    }
}

// ---------------------------------------------------------------------------
extern "C" void kernel_launch(void* const* d_in, const int* in_sizes, int n_in,
                              void* d_out, int out_size, void* d_ws, size_t ws_size,
                              hipStream_t stream)
{
    (void)in_sizes; (void)n_in; (void)out_size; (void)ws_size;

    const float* x_in = (const float*)d_in[0];
    const float* mask = (const float*)d_in[1];
    const float* Wq = (const float*)d_in[5];
    const float* bq = (const float*)d_in[6];
    const float* Wk = (const float*)d_in[7];
    const float* bk = (const float*)d_in[8];
    const float* Wv = (const float*)d_in[9];
    const float* bv = (const float*)d_in[10];
    const float* Wo = (const float*)d_in[11];
    const float* bo = (const float*)d_in[12];
    const float* g1 = (const float*)d_in[13];
    const float* b1 = (const float*)d_in[14];
    const float* g2 = (const float*)d_in[15];
    const float* b2 = (const float*)d_in[16];

    float* out_x = (float*)d_out;
    float* out_l1 = out_x + kSZ;
    float* out_w = out_l1 + 1;

    char* wsb = (char*)d_ws;
    __bf16* Qb = (__bf16*)wsb;
    __bf16* Kb = (__bf16*)(wsb + 1 * kSZ * 2);
    __bf16* Vb = (__bf16*)(wsb + 2 * kSZ * 2);
    __bf16* O1 = (__bf16*)(wsb + 3 * kSZ * 2);
    __bf16* xb = (__bf16*)(wsb + 4 * kSZ * 2);
    __bf16* Wt = (__bf16*)(wsb + 5 * kSZ * 2);   // 8 * 16384 bf16

    wtrans<<<8, 256, 0, stream>>>(Wq, Wk, Wv, Wo, Wt);

    // ---- layer 0 (f32 x_in) ----
    qkv_gemm<true><<<256, 512, 0, stream>>>(x_in, Wt, bq, bk, bv, Qb, Kb, Vb);
    attn_oproj<0, true><<<256, 512, 0, stream>>>(Qb, Kb, Vb, mask,
                                                 Wt + 3 * kD * kD, bo,
                                                 x_in, g1, b1, O1,
                                                 nullptr, nullptr);
    tree_ln<<<128, 1024, 0, stream>>>(O1, g2, b2, nullptr, xb, 0, 1);

    // ---- layer 1 (bf16 xb) ----
    const __bf16* WtL = Wt + 4 * kD * kD;
    qkv_gemm<false><<<256, 512, 0, stream>>>(xb, WtL, bq + kD, bk + kD, bv + kD,
                                             Qb, Kb, Vb);
    attn_oproj<1, false><<<256, 512, 0, stream>>>(Qb, Kb, Vb, mask,
                                                  WtL + 3 * kD * kD, bo + kD,
                                                  xb, g1 + kD, b1 + kD, O1,
                                                  out_w, out_l1);
    tree_ln<<<128, 1024, 0, stream>>>(O1, g2 + kD, b2 + kD, out_x, nullptr, 1, 0);
}

// Round 8
// 132.975 us; speedup vs baseline: 1.7927x; 1.0006x over previous
//
#include <hip/hip_runtime.h>
#include <math.h>

typedef __bf16 bf16x8 __attribute__((ext_vector_type(8)));
typedef __bf16 bf16x2 __attribute__((ext_vector_type(2)));
typedef float f32x4 __attribute__((ext_vector_type(4)));

namespace {
constexpr int kB = 128, kS = 256, kD = 128, kH = 4;
constexpr float kEps = 1e-6f;
constexpr float kScale = 0.17677669529663687f;  // 1/sqrt(32)
constexpr float kNeg = -1000000000.0f;
constexpr size_t kSZ = (size_t)kB * kS * kD;    // 4,194,304
}

// ---------------------------------------------------------------------------
// Weight transpose + convert: Wt[l*4+mtx][n][k] = (bf16) W[l][k][n]
// ---------------------------------------------------------------------------
__global__ __launch_bounds__(256) void wtrans(
    const float* __restrict__ Wq, const float* __restrict__ Wk,
    const float* __restrict__ Wv, const float* __restrict__ Wo,
    __bf16* __restrict__ Wt)
{
    const int mtx = blockIdx.x & 3, l = blockIdx.x >> 2;
    const float* W = (mtx == 0 ? Wq : mtx == 1 ? Wk : mtx == 2 ? Wv : Wo) +
                     (size_t)l * kD * kD;
    __bf16* o = Wt + (size_t)blockIdx.x * kD * kD;
    for (int idx = threadIdx.x; idx < kD * kD; idx += 256) {
        const int k = idx >> 7, n = idx & 127;
        o[n * 128 + k] = (__bf16)W[idx];
    }
}

// ---------------------------------------------------------------------------
// Fused QKV GEMM, 64KB LDS: A tile + ONE W tile re-staged for each of Q,K,V.
// A source is f32 (layer 0) or bf16 (layer 1). (round-5/6 known-good body)
// ---------------------------------------------------------------------------
template <bool F32A>
__global__ __launch_bounds__(512, 4) void qkv_gemm(
    const void* __restrict__ Av, const __bf16* __restrict__ Wt,
    const float* __restrict__ bq, const float* __restrict__ bk,
    const float* __restrict__ bv, __bf16* __restrict__ Qb,
    __bf16* __restrict__ Kb, __bf16* __restrict__ Vb)
{
    __shared__ __bf16 As[128 * 128];
    __shared__ __bf16 Ws[128 * 128];

    const int t = threadIdx.x;
    const int w = t >> 6, l = t & 63, lo = l & 15, g = l >> 4;
    const size_t m0 = (size_t)blockIdx.x * 128;

#pragma unroll
    for (int p = 0; p < 4; ++p) {
        const int ci = p * 512 + t;
        const int row = ci >> 4, c = ci & 15;
        if constexpr (F32A) {
            const float* src = (const float*)Av + (m0 + row) * 128 + c * 8;
            const float4 a0 = *(const float4*)src;
            const float4 a1 = *(const float4*)(src + 4);
            bf16x8 o;
            o[0] = (__bf16)a0.x; o[1] = (__bf16)a0.y; o[2] = (__bf16)a0.z; o[3] = (__bf16)a0.w;
            o[4] = (__bf16)a1.x; o[5] = (__bf16)a1.y; o[6] = (__bf16)a1.z; o[7] = (__bf16)a1.w;
            *(bf16x8*)&As[row * 128 + (c ^ (row & 7)) * 8] = o;
        } else {
            *(bf16x8*)&As[row * 128 + (c ^ (row & 7)) * 8] =
                *(const bf16x8*)((const __bf16*)Av + (m0 + row) * 128 + c * 8);
        }
    }
#pragma unroll
    for (int p = 0; p < 4; ++p) {
        const int ci = p * 512 + t;
        const int row = ci >> 4, c = ci & 15;
        *(bf16x8*)&Ws[row * 128 + (c ^ (row & 7)) * 8] =
            *(const bf16x8*)(Wt + row * 128 + c * 8);
    }
    __syncthreads();

    bf16x8 av[4];
    {
        const int arow = w * 16 + lo;
#pragma unroll
        for (int ks = 0; ks < 4; ++ks)
            av[ks] = *(const bf16x8*)&As[arow * 128 + ((g + 4 * ks) ^ (arow & 7)) * 8];
    }

    const float* biases[3] = {bq, bk, bv};
    __bf16* outs[3] = {Qb, Kb, Vb};

#pragma unroll
    for (int m = 0; m < 3; ++m) {
        f32x4 acc[8];
#pragma unroll
        for (int ni = 0; ni < 8; ++ni) acc[ni] = f32x4{0.f, 0.f, 0.f, 0.f};
#pragma unroll
        for (int ks = 0; ks < 4; ++ks)
#pragma unroll
            for (int ni = 0; ni < 8; ++ni) {
                const int brow = ni * 16 + lo;
                const bf16x8 bv8 =
                    *(const bf16x8*)&Ws[brow * 128 + ((g + 4 * ks) ^ (brow & 7)) * 8];
                acc[ni] = __builtin_amdgcn_mfma_f32_16x16x32_bf16(av[ks], bv8, acc[ni], 0, 0, 0);
            }
#pragma unroll
        for (int ni = 0; ni < 8; ++ni) {
            const float bc = biases[m][ni * 16 + lo];
#pragma unroll
            for (int r = 0; r < 4; ++r)
                outs[m][(m0 + w * 16 + g * 4 + r) * 128 + ni * 16 + lo] =
                    (__bf16)(acc[ni][r] + bc);
        }
        if (m < 2) {
            __syncthreads();
#pragma unroll
            for (int p = 0; p < 4; ++p) {
                const int ci = p * 512 + t;
                const int row = ci >> 4, c = ci & 15;
                *(bf16x8*)&Ws[row * 128 + (c ^ (row & 7)) * 8] =
                    *(const bf16x8*)(Wt + (m + 1) * 16384 + row * 128 + c * 8);
            }
            __syncthreads();
        }
    }
}

// ---------------------------------------------------------------------------
// FUSED attention + O-projection + residual + LayerNorm1.
// Grid 256, STRIP-MAJOR: bid = strip*128 + b, so both strips of batch b land
// on the same XCD (128 % 8 == 0) -> second K/V read is an L2 hit (T1).
// 512 threads = 8 waves x 16 queries. T14 async-stage for next head's K/V.
// RESF32: residual source f32 (layer0) or bf16 (layer1).
// WEIGHTS: wave holding q=255 emits softmax rows; total_l1 = 1024 exactly.
// ---------------------------------------------------------------------------
template <int WEIGHTS, bool RESF32>
__global__ __launch_bounds__(512) void attn_oproj(
    const __bf16* __restrict__ Qb, const __bf16* __restrict__ Kb,
    const __bf16* __restrict__ Vb, const float* __restrict__ mask,
    const __bf16* __restrict__ Wo, const float* __restrict__ bo,
    const void* __restrict__ resid, const float* __restrict__ gamma,
    const float* __restrict__ beta, __bf16* __restrict__ O1,
    float* __restrict__ wout, float* __restrict__ l1out)
{
    __shared__ __bf16 Kls[256 * 32];   // [key][32], 4 chunks/row XOR-swizzled
    __shared__ __bf16 Vt[32][270];     // V^T [d][key]
    __shared__ __bf16 Pl[8][16 * 128]; // per-wave half-P, swizzled chunks
    __shared__ __bf16 Ctx[128 * 128];  // swizzled ctx tile
    __shared__ __bf16 Wos[128 * 128];  // swizzled Wo
    __shared__ float mb[256];

    const int t = threadIdx.x;
    const int w = t >> 6, l = t & 63, lo = l & 15, g = l >> 4;
    const int b = blockIdx.x & 127, strip = blockIdx.x >> 7;  // strip-major
    const size_t bbase = (size_t)b * 256 * 128;
    const int q0 = strip * 128 + w * 16;
    const int kswz = (lo ^ (lo >> 2)) & 3;

    // prefetch registers for K/V staging (T14)
    bf16x8 kpre[2], vpre[2];
    const int krow = t >> 2, kc = t & 3;          // K: 2 chunks/thread
    const int vkey = t >> 2, vd0 = (t & 3) << 3;  // V: 2 chunks/thread

    auto loadKV = [&](int h) {
#pragma unroll
        for (int p = 0; p < 2; ++p)
            kpre[p] = *(const bf16x8*)(Kb + bbase + (size_t)(p * 128 + krow) * 128 +
                                       h * 32 + kc * 8);
#pragma unroll
        for (int p = 0; p < 2; ++p)
            vpre[p] = *(const bf16x8*)(Vb + bbase + (size_t)(p * 128 + vkey) * 128 +
                                       h * 32 + vd0);
    };
    auto writeKV = [&]() {
#pragma unroll
        for (int p = 0; p < 2; ++p) {
            const int row = p * 128 + krow;
            const int sw = (kc ^ ((row ^ (row >> 2)) & 3)) << 3;
            *(bf16x8*)&Kls[row * 32 + sw] = kpre[p];
        }
#pragma unroll
        for (int p = 0; p < 2; ++p) {
            const int key = p * 128 + vkey;
#pragma unroll
            for (int i = 0; i < 8; ++i) Vt[vd0 + i][key] = vpre[p][i];
        }
    };

    // stage Wo once (swizzled)
#pragma unroll
    for (int p = 0; p < 4; ++p) {
        const int ci = p * 512 + t;
        const int row = ci >> 4, c = ci & 15;
        *(bf16x8*)&Wos[row * 128 + ((c ^ (row & 7)) << 3)] =
            *(const bf16x8*)(Wo + row * 128 + c * 8);
    }
    if (t < 256) mb[t] = mask[b * 256 + t] * kNeg;
    if (WEIGHTS && blockIdx.x == 0 && t == 0) l1out[0] = 1024.0f;

    // all 4 Q head-fragments up front
    bf16x8 qfr[4];
#pragma unroll
    for (int h = 0; h < 4; ++h)
        qfr[h] = *(const bf16x8*)(Qb + bbase + (size_t)(q0 + lo) * 128 + h * 32 + g * 8);

    loadKV(0);
    writeKV();
    __syncthreads();

#pragma unroll
    for (int h = 0; h < 4; ++h) {
        // S^T = K @ Q^T  (16 key-frags)
        f32x4 s[16];
#pragma unroll
        for (int f = 0; f < 16; ++f) {
            const bf16x8 kf =
                *(const bf16x8*)&Kls[(f * 16 + lo) * 32 + ((g ^ kswz) << 3)];
            s[f] = __builtin_amdgcn_mfma_f32_16x16x32_bf16(
                kf, qfr[h], f32x4{0.f, 0.f, 0.f, 0.f}, 0, 0, 0);
        }

        if (h < 3) loadKV(h + 1);  // T14: issue next head's K/V now

        float mx = -1e30f;
#pragma unroll
        for (int f = 0; f < 16; ++f) {
            const f32x4 mk = *(const f32x4*)&mb[f * 16 + g * 4];
#pragma unroll
            for (int r = 0; r < 4; ++r) {
                s[f][r] = s[f][r] * kScale + mk[r];
                mx = fmaxf(mx, s[f][r]);
            }
        }
        mx = fmaxf(mx, __shfl_xor(mx, 16, 64));
        mx = fmaxf(mx, __shfl_xor(mx, 32, 64));

        float ls = 0.f;
#pragma unroll
        for (int f = 0; f < 16; ++f)
#pragma unroll
            for (int r = 0; r < 4; ++r) {
                const float p = __expf(s[f][r] - mx);
                s[f][r] = p;
                ls += p;
            }
        ls += __shfl_xor(ls, 16, 64);
        ls += __shfl_xor(ls, 32, 64);

        if constexpr (WEIGHTS) {
            if (strip == 1 && w == 7 && lo == 15) {
                const float inv = 1.f / ls;
                float* wrow = wout + ((size_t)b * 4 + h) * 256;
#pragma unroll
                for (int f = 0; f < 16; ++f)
#pragma unroll
                    for (int r = 0; r < 4; ++r)
                        wrow[f * 16 + g * 4 + r] = s[f][r] * inv;
            }
        }

        // PV in two half-P passes (keys 0..127, 128..255)
        f32x4 o[2] = {f32x4{0.f, 0.f, 0.f, 0.f}, f32x4{0.f, 0.f, 0.f, 0.f}};
#pragma unroll
        for (int half = 0; half < 2; ++half) {
#pragma unroll
            for (int f = 0; f < 8; ++f) {
                const int ff = half * 8 + f;
#pragma unroll
                for (int pr = 0; pr < 2; ++pr) {
                    bf16x2 pk;
                    pk[0] = (__bf16)s[ff][2 * pr];
                    pk[1] = (__bf16)s[ff][2 * pr + 1];
                    const int e = f * 16 + 4 * g + 2 * pr;
                    const int addr =
                        lo * 128 + ((((e >> 3) ^ (lo & 7)) << 3) | (e & 7));
                    *(bf16x2*)&Pl[w][addr] = pk;
                }
            }
#pragma unroll
            for (int ks = 0; ks < 4; ++ks) {
                const int cc = ks * 4 + g;
                const bf16x8 pa =
                    *(const bf16x8*)&Pl[w][lo * 128 + ((cc ^ (lo & 7)) << 3)];
#pragma unroll
                for (int nf = 0; nf < 2; ++nf) {
                    const bf16x8 bv =
                        *(const bf16x8*)&Vt[nf * 16 + lo][(half * 4 + ks) * 32 + g * 8];
                    o[nf] = __builtin_amdgcn_mfma_f32_16x16x32_bf16(pa, bv, o[nf], 0, 0, 0);
                }
            }
        }

        // normalized ctx -> swizzled LDS tile (cols h*32..h*32+31)
#pragma unroll
        for (int r = 0; r < 4; ++r) {
            const float inv = 1.f / __shfl(ls, 4 * g + r, 64);
            const int crow = w * 16 + g * 4 + r;
#pragma unroll
            for (int nf = 0; nf < 2; ++nf) {
                const int col = h * 32 + nf * 16 + lo;
                const int chunk = (col >> 3) ^ (crow & 7);
                Ctx[crow * 128 + (chunk << 3) + (col & 7)] = (__bf16)(o[nf][r] * inv);
            }
        }
        if (h < 3) {
            __syncthreads();   // all Kls/Vt reads of head h complete
            writeKV();         // regs -> LDS for head h+1
            __syncthreads();
        }
        // (no barrier after h==3: oproj A-frags read only this wave's Ctx rows)
    }

    // ---- O-projection + residual + LN1 (wave = 16 rows) ----
    const size_t m0 = (size_t)b * 256 + strip * 128;
    f32x4 acc[8];
#pragma unroll
    for (int ni = 0; ni < 8; ++ni) acc[ni] = f32x4{0.f, 0.f, 0.f, 0.f};

    const int arow = w * 16 + lo;
#pragma unroll
    for (int ks = 0; ks < 4; ++ks) {
        const bf16x8 av =
            *(const bf16x8*)&Ctx[arow * 128 + (((g + 4 * ks) ^ (arow & 7)) << 3)];
#pragma unroll
        for (int ni = 0; ni < 8; ++ni) {
            const int brow = ni * 16 + lo;
            const bf16x8 bv8 =
                *(const bf16x8*)&Wos[brow * 128 + (((g + 4 * ks) ^ (brow & 7)) << 3)];
            acc[ni] = __builtin_amdgcn_mfma_f32_16x16x32_bf16(av, bv8, acc[ni], 0, 0, 0);
        }
    }

    float bcol[8], ga[8], be[8];
#pragma unroll
    for (int ni = 0; ni < 8; ++ni) {
        bcol[ni] = bo[ni * 16 + lo];
        ga[ni] = gamma[ni * 16 + lo];
        be[ni] = beta[ni * 16 + lo];
    }

    float vv[4][8];
    float s[4] = {0, 0, 0, 0}, s2[4] = {0, 0, 0, 0};
#pragma unroll
    for (int r = 0; r < 4; ++r) {
        const size_t mm = m0 + w * 16 + g * 4 + r;
#pragma unroll
        for (int ni = 0; ni < 8; ++ni) {
            float rv;
            if constexpr (RESF32)
                rv = ((const float*)resid)[mm * 128 + ni * 16 + lo];
            else
                rv = (float)((const __bf16*)resid)[mm * 128 + ni * 16 + lo];
            const float x = acc[ni][r] + bcol[ni] + rv;
            vv[r][ni] = x; s[r] += x; s2[r] += x * x;
        }
    }
#pragma unroll
    for (int r = 0; r < 4; ++r)
#pragma unroll
        for (int o = 1; o < 16; o <<= 1) {
            s[r] += __shfl_xor(s[r], o, 64);
            s2[r] += __shfl_xor(s2[r], o, 64);
        }
#pragma unroll
    for (int r = 0; r < 4; ++r) {
        const float mu = s[r] * (1.f / 128.f);
        const float var = s2[r] * (1.f / 128.f) - mu * mu;
        const float rs = rsqrtf(var + kEps);
        const size_t mm = m0 + w * 16 + g * 4 + r;
#pragma unroll
        for (int ni = 0; ni < 8; ++ni)
            O1[mm * 128 + ni * 16 + lo] =
                (__bf16)(ga[ni] * (vv[r][ni] - mu) * rs + be[ni]);
    }
}

// ---------------------------------------------------------------------------
// FUSED tree aggregation + residual + LayerNorm2. One block per batch.
// e[255][132] f32 in LDS. PER-WAVE tree: wave w owns feature cols
// [w*8, w*8+8); features are independent, so all 7 levels run with NO block
// barrier (intra-wave LDS RAW handled by lgkmcnt). Only 2 barriers total:
// post-stage and pre-LN. LN per row as before.
// ---------------------------------------------------------------------------
__global__ __launch_bounds__(1024) void tree_ln(
    const __bf16* __restrict__ o1, const float* __restrict__ gamma,
    const float* __restrict__ beta, float* __restrict__ xo,
    __bf16* __restrict__ xb, int wf32, int wbf16)
{
    __shared__ float e[255 * 132];
    const int b = blockIdx.x;
    const int t = threadIdx.x;
    const __bf16* ob = o1 + (size_t)b * 256 * 128;

    // stage 255 rows (4080 bf16x8 chunks) -> f32 LDS (coalesced)
#pragma unroll
    for (int p = 0; p < 4; ++p) {
        const int ci = p * 1024 + t;
        if (ci < 4080) {
            const int row = ci >> 4, c8 = (ci & 15) * 8;
            const bf16x8 v = *(const bf16x8*)(ob + ci * 8);
            float* dst = &e[row * 132 + c8];
#pragma unroll
            for (int i = 0; i < 8; ++i) dst[i] = (float)v[i];
        }
    }
    __syncthreads();

    // per-wave barrier-free tree: wave w -> cols w*8..w*8+7
    {
        const int wv = t >> 6, ln = t & 63;
        const int col = wv * 8 + (ln & 7);
        const int nsub = ln >> 3;  // node sub-index 0..7
        for (int lvl = 6; lvl >= 0; --lvl) {
            const int p0 = (1 << lvl) - 1;
            const int cnt = 1 << lvl;
            for (int base = 0; base < cnt; base += 8) {
                const int p = p0 + base + nsub;
                if (base + nsub < cnt) {
                    e[p * 132 + col] =
                        tanhf(e[(2 * p + 1) * 132 + col] + e[(2 * p + 2) * 132 + col]);
                }
            }
        }
    }
    __syncthreads();

    // y = out1 + tab; LayerNorm per row (wave per row, 2 cols/lane)
    const int wv = t >> 6, lane = t & 63;
    const float2 gv = *(const float2*)(gamma + lane * 2);
    const float2 bb = *(const float2*)(beta + lane * 2);
    for (int row = wv; row < 256; row += 16) {
        const int c = lane * 2;
        float y0, y1;
        if (row >= 127 && row < 255) {
            // leaf rows: e holds original out1; tab == out1
            y0 = 2.f * e[row * 132 + c];
            y1 = 2.f * e[row * 132 + c + 1];
        } else if (row < 127) {
            // internal: original out1 from global, tab from (overwritten) e
            const bf16x2 v = *(const bf16x2*)(ob + (size_t)row * 128 + c);
            y0 = (float)v[0] + e[row * 132 + c];
            y1 = (float)v[1] + e[row * 132 + c + 1];
        } else {  // row == 255: pass-through, tab == out1
            const bf16x2 v = *(const bf16x2*)(ob + (size_t)row * 128 + c);
            y0 = 2.f * (float)v[0];
            y1 = 2.f * (float)v[1];
        }
        float s = y0 + y1, s2 = y0 * y0 + y1 * y1;
#pragma unroll
        for (int o = 1; o < 64; o <<= 1) {
            s += __shfl_xor(s, o, 64);
            s2 += __shfl_xor(s2, o, 64);
        }
        const float mu = s * (1.f / 128.f);
        const float var = s2 * (1.f / 128.f) - mu * mu;
        const float rs = rsqrtf(var + kEps);
        const float r0 = gv.x * (y0 - mu) * rs + bb.x;
        const float r1 = gv.y * (y1 - mu) * rs + bb.y;
        const size_t off = ((size_t)b * 256 + row) * 128 + c;
        if (wf32) {
            float2 o2; o2.x = r0; o2.y = r1;
            *(float2*)(xo + off) = o2;
        }
        if (wbf16) {
            bf16x2 ob2; ob2[0] = (__bf16)r0; ob2[1] = (__bf16)r1;
            *(bf16x2*)(xb + off) = ob2;
        }
    }
}

// ---------------------------------------------------------------------------
extern "C" void kernel_launch(void* const* d_in, const int* in_sizes, int n_in,
                              void* d_out, int out_size, void* d_ws, size_t ws_size,
                              hipStream_t stream)
{
    (void)in_sizes; (void)n_in; (void)out_size; (void)ws_size;

    const float* x_in = (const float*)d_in[0];
    const float* mask = (const float*)d_in[1];
    const float* Wq = (const float*)d_in[5];
    const float* bq = (const float*)d_in[6];
    const float* Wk = (const float*)d_in[7];
    const float* bk = (const float*)d_in[8];
    const float* Wv = (const float*)d_in[9];
    const float* bv = (const float*)d_in[10];
    const float* Wo = (const float*)d_in[11];
    const float* bo = (const float*)d_in[12];
    const float* g1 = (const float*)d_in[13];
    const float* b1 = (const float*)d_in[14];
    const float* g2 = (const float*)d_in[15];
    const float* b2 = (const float*)d_in[16];

    float* out_x = (float*)d_out;
    float* out_l1 = out_x + kSZ;
    float* out_w = out_l1 + 1;

    char* wsb = (char*)d_ws;
    __bf16* Qb = (__bf16*)wsb;
    __bf16* Kb = (__bf16*)(wsb + 1 * kSZ * 2);
    __bf16* Vb = (__bf16*)(wsb + 2 * kSZ * 2);
    __bf16* O1 = (__bf16*)(wsb + 3 * kSZ * 2);
    __bf16* xb = (__bf16*)(wsb + 4 * kSZ * 2);
    __bf16* Wt = (__bf16*)(wsb + 5 * kSZ * 2);   // 8 * 16384 bf16

    wtrans<<<8, 256, 0, stream>>>(Wq, Wk, Wv, Wo, Wt);

    // ---- layer 0 (f32 x_in) ----
    qkv_gemm<true><<<256, 512, 0, stream>>>(x_in, Wt, bq, bk, bv, Qb, Kb, Vb);
    attn_oproj<0, true><<<256, 512, 0, stream>>>(Qb, Kb, Vb, mask,
                                                 Wt + 3 * kD * kD, bo,
                                                 x_in, g1, b1, O1,
                                                 nullptr, nullptr);
    tree_ln<<<128, 1024, 0, stream>>>(O1, g2, b2, nullptr, xb, 0, 1);

    // ---- layer 1 (bf16 xb) ----
    const __bf16* WtL = Wt + 4 * kD * kD;
    qkv_gemm<false><<<256, 512, 0, stream>>>(xb, WtL, bq + kD, bk + kD, bv + kD,
                                             Qb, Kb, Vb);
    attn_oproj<1, false><<<256, 512, 0, stream>>>(Qb, Kb, Vb, mask,
                                                  WtL + 3 * kD * kD, bo + kD,
                                                  xb, g1 + kD, b1 + kD, O1,
                                                  out_w, out_l1);
    tree_ln<<<128, 1024, 0, stream>>>(O1, g2 + kD, b2 + kD, out_x, nullptr, 1, 0);
}